// Round 12
// baseline (16097.723 us; speedup 1.0000x reference)
//
#include <hip/hip_runtime.h>
#include <math.h>

// N=2048 nodes, E=1024 edges, F=512 hidden, C=40 classes, 10 layers
// out: [81920 log_probs][10 energies][10 energies_exp][10 snorms][1 gap]

typedef __attribute__((ext_vector_type(8))) short short8;
typedef __attribute__((ext_vector_type(4))) float f32x4;

#define NSHIFT 256

__device__ inline ushort bf16_rne(float f) {
    unsigned int u = __float_as_uint(f);
    return (ushort)((u + 0x7FFFu + ((u >> 16) & 1u)) >> 16);
}
__device__ inline float bf16_tof(ushort h) {
    return __uint_as_float(((unsigned int)h) << 16);
}

// ---------------------------------------------------------------------------
// Contention-free grid barrier (used ONLY by mlp_persist; 36 barriers total)
// ---------------------------------------------------------------------------
__device__ __forceinline__ void pbar(int* bar, int e, int w, int nwg) {
    __syncthreads();
    if (threadIdx.x == 0) {
        __threadfence();
        __hip_atomic_store(bar + 16 + w*16, e, __ATOMIC_RELAXED, __HIP_MEMORY_SCOPE_AGENT);
    }
    if (w == 0) {
        if ((int)threadIdx.x < nwg) {
            while (__hip_atomic_load(bar + 16 + threadIdx.x*16, __ATOMIC_RELAXED,
                                     __HIP_MEMORY_SCOPE_AGENT) < e)
                __builtin_amdgcn_s_sleep(1);
        }
        __syncthreads();
        if (threadIdx.x == 0)
            __hip_atomic_store(bar, e, __ATOMIC_RELEASE, __HIP_MEMORY_SCOPE_AGENT);
    } else {
        if (threadIdx.x == 0) {
            while (__hip_atomic_load(bar, __ATOMIC_RELAXED, __HIP_MEMORY_SCOPE_AGENT) < e)
                __builtin_amdgcn_s_sleep(8);
        }
    }
    if (threadIdx.x == 0) __threadfence();
    __syncthreads();
}

__global__ void init_misc(int* bar) {
    for (int j = blockIdx.x*256 + threadIdx.x; j < 16384; j += gridDim.x*256) bar[j] = 0;
}

// ---------------------------------------------------------------------------
// 64x64 f32 tile MAC, single-buffered (mlp_persist uses this)
// ---------------------------------------------------------------------------
template<bool TA, bool TB>
__device__ __forceinline__
void tile64g(const float* __restrict__ A, int lda,
             const float* __restrict__ B, int ldb,
             int bm, int bn, int k0, int k1, float acc[4][4],
             float (*sA)[68], float (*sB)[68])
{
    const int tid = threadIdx.x;
    const int tx = tid & 15, ty = tid >> 4;
    for (int kk = k0; kk < k1; kk += 16) {
        __syncthreads();
        for (int i = tid; i < 1024; i += 256) {
            int m, k2;
            if (TA) { m = i & 63; k2 = i >> 6; } else { k2 = i & 15; m = i >> 4; }
            sA[k2][m] = TA ? A[(size_t)(kk + k2)*lda + bm + m]
                           : A[(size_t)(bm + m)*lda + kk + k2];
        }
        for (int i = tid; i < 1024; i += 256) {
            int n, k2;
            if (TB) { k2 = i & 15; n = i >> 4; } else { n = i & 63; k2 = i >> 6; }
            sB[k2][n] = TB ? B[(size_t)(bn + n)*ldb + kk + k2]
                           : B[(size_t)(kk + k2)*ldb + bn + n];
        }
        __syncthreads();
        #pragma unroll
        for (int k2 = 0; k2 < 16; ++k2) {
            float4 a4 = *(const float4*)&sA[k2][ty*4];
            float4 b4 = *(const float4*)&sB[k2][tx*4];
            float av[4] = {a4.x, a4.y, a4.z, a4.w};
            float bv[4] = {b4.x, b4.y, b4.z, b4.w};
            #pragma unroll
            for (int i2 = 0; i2 < 4; ++i2)
                #pragma unroll
                for (int j2 = 0; j2 < 4; ++j2)
                    acc[i2][j2] += av[i2] * bv[j2];
        }
    }
}

// ---------------------------------------------------------------------------
// 64x64 f32 tile MAC, DOUBLE-BUFFERED register prefetch.
// ---------------------------------------------------------------------------
template<bool TA, bool TB>
__device__ __forceinline__
void tile64d(const float* __restrict__ A, int lda,
             const float* __restrict__ B, int ldb,
             int bm, int bn, int k0, int k1, float acc[4][4],
             float (*sA)[16][68], float (*sB)[16][68])
{
    const int tid = threadIdx.x;
    const int tx = tid & 15, ty = tid >> 4;
    float ra[4], rb[4];
    auto ldregs = [&](int kk) {
        #pragma unroll
        for (int q = 0; q < 4; ++q) {
            int i = tid + q*256;
            if (TA) { int m = i & 63, k2 = i >> 6; ra[q] = A[(size_t)(kk + k2)*lda + bm + m]; }
            else    { int k2 = i & 15, m = i >> 4; ra[q] = A[(size_t)(bm + m)*lda + kk + k2]; }
            if (TB) { int k3 = i & 15, n = i >> 4; rb[q] = B[(size_t)(bn + n)*ldb + kk + k3]; }
            else    { int k3 = i >> 6, n = i & 63; rb[q] = B[(size_t)(kk + k3)*ldb + bn + n]; }
        }
    };
    auto stlds = [&](int buf) {
        #pragma unroll
        for (int q = 0; q < 4; ++q) {
            int i = tid + q*256;
            if (TA) { int m = i & 63, k2 = i >> 6; sA[buf][k2][m] = ra[q]; }
            else    { int k2 = i & 15, m = i >> 4; sA[buf][k2][m] = ra[q]; }
            if (TB) { int k3 = i & 15, n = i >> 4; sB[buf][k3][n] = rb[q]; }
            else    { int k3 = i >> 6, n = i & 63; sB[buf][k3][n] = rb[q]; }
        }
    };
    const int nit = (k1 - k0) >> 4;
    ldregs(k0);
    stlds(0);
    for (int it = 0; it < nit; ++it) {
        const int buf = it & 1;
        if (it + 1 < nit) ldregs(k0 + (it + 1)*16);
        __syncthreads();
        #pragma unroll
        for (int k2 = 0; k2 < 16; ++k2) {
            float4 a4 = *(const float4*)&sA[buf][k2][ty*4];
            float4 b4 = *(const float4*)&sB[buf][k2][tx*4];
            float av[4] = {a4.x, a4.y, a4.z, a4.w};
            float bv[4] = {b4.x, b4.y, b4.z, b4.w};
            #pragma unroll
            for (int i2 = 0; i2 < 4; ++i2)
                #pragma unroll
                for (int j2 = 0; j2 < 4; ++j2)
                    acc[i2][j2] += av[i2] * bv[j2];
        }
        if (it + 1 < nit) { __syncthreads(); stlds(buf ^ 1); }
    }
}

// Variant: B(k,n) = sum_{z<8} Bp[z*131072 + k*64 + n]  (inline split-K merge,
// z-order 0..7 identical to the old materializing reduction kernels)
template<bool TA>
__device__ __forceinline__
void tile64dsum(const float* __restrict__ A, int lda,
                const float* __restrict__ Bp,
                int bm, int k0, int k1, float acc[4][4],
                float (*sA)[16][68], float (*sB)[16][68])
{
    const int tid = threadIdx.x;
    const int tx = tid & 15, ty = tid >> 4;
    float ra[4], rb[4];
    auto ldregs = [&](int kk) {
        #pragma unroll
        for (int q = 0; q < 4; ++q) {
            int i = tid + q*256;
            if (TA) { int m = i & 63, k2 = i >> 6; ra[q] = A[(size_t)(kk + k2)*lda + bm + m]; }
            else    { int k2 = i & 15, m = i >> 4; ra[q] = A[(size_t)(bm + m)*lda + kk + k2]; }
            int k3 = i >> 6, n = i & 63;
            size_t o = (size_t)(kk + k3)*64 + n;
            float v = 0.f;
            #pragma unroll
            for (int z = 0; z < 8; ++z) v += Bp[(size_t)z*131072 + o];
            rb[q] = v;
        }
    };
    auto stlds = [&](int buf) {
        #pragma unroll
        for (int q = 0; q < 4; ++q) {
            int i = tid + q*256;
            if (TA) { int m = i & 63, k2 = i >> 6; sA[buf][k2][m] = ra[q]; }
            else    { int k2 = i & 15, m = i >> 4; sA[buf][k2][m] = ra[q]; }
            int k3 = i >> 6, n = i & 63;
            sB[buf][k3][n] = rb[q];
        }
    };
    const int nit = (k1 - k0) >> 4;
    ldregs(k0);
    stlds(0);
    for (int it = 0; it < nit; ++it) {
        const int buf = it & 1;
        if (it + 1 < nit) ldregs(k0 + (it + 1)*16);
        __syncthreads();
        #pragma unroll
        for (int k2 = 0; k2 < 16; ++k2) {
            float4 a4 = *(const float4*)&sA[buf][k2][ty*4];
            float4 b4 = *(const float4*)&sB[buf][k2][tx*4];
            float av[4] = {a4.x, a4.y, a4.z, a4.w};
            float bv[4] = {b4.x, b4.y, b4.z, b4.w};
            #pragma unroll
            for (int i2 = 0; i2 < 4; ++i2)
                #pragma unroll
                for (int j2 = 0; j2 < 4; ++j2)
                    acc[i2][j2] += av[i2] * bv[j2];
        }
        if (it + 1 < nit) { __syncthreads(); stlds(buf ^ 1); }
    }
}

__device__ __forceinline__ void store_tile(float* C, int ldc, int bm, float acc[4][4]) {
    int tx = threadIdx.x & 15, ty = threadIdx.x >> 4;
    #pragma unroll
    for (int i = 0; i < 4; ++i)
        #pragma unroll
        for (int j = 0; j < 4; ++j)
            C[(size_t)(bm + ty*4 + i)*ldc + tx*4 + j] = acc[i][j];
}

// ---------------------------------------------------------------------------
// Block-Lanczos step kernels (6 graph-chained kernels/step)
// Buffers: Cp (LQ partials) -> uB (QTZ partials) -> hB (QC partials)
// ---------------------------------------------------------------------------
__global__ void init_q0(float* Q) {
    int idx = blockIdx.x*256 + threadIdx.x;
    if (idx < 2048*64) {
        int n = idx >> 6, c = idx & 63;
        Q[(size_t)n*2048 + c] = (n == c) ? 1.f : 0.f;
    }
}

// Cp[z] = L(rows mt*64..)*Qs over K-chunk [z*256, z*256+256)
__global__ __launch_bounds__(256)
void lz_LQ(const float* __restrict__ Lm, const float* __restrict__ Qs, float* __restrict__ Cp)
{
    __shared__ float sA[2][16][68], sB[2][16][68];
    int z = blockIdx.x, mt = blockIdx.y;
    float acc[4][4] = {};
    tile64d<false,false>(Lm, 2048, Qs, 2048, mt*64, 0, z*256, z*256 + 256, acc, sA, sB);
    store_tile(Cp + (size_t)z*131072, 64, mt*64, acc);
}

// uB[z](rows b*64..) = Q(:,b-block)^T * (sum_z' Cp[z']) over K-chunk z*256
__global__ __launch_bounds__(256)
void lz_QTZs(const float* __restrict__ Qall, const float* __restrict__ Cp,
             float* __restrict__ uB)
{
    __shared__ float sA[2][16][68], sB[2][16][68];
    int z = blockIdx.x, b = blockIdx.y;
    float acc[4][4] = {};
    tile64dsum<true>(Qall, 2048, Cp, b*64, z*256, z*256 + 256, acc, sA, sB);
    store_tile(uB + (size_t)z*131072, 64, b*64, acc);
}

// hB[z] = Q(rows mt)(blocks j==z mod 8, j<=s) * (sum_z' uB[z'])(blocks j)
__global__ __launch_bounds__(256)
void lz_QCs(const float* __restrict__ Qall, const float* __restrict__ uB,
            float* __restrict__ hB, int s)
{
    __shared__ float sA[2][16][68], sB[2][16][68];
    int z = blockIdx.x, mt = blockIdx.y;   // gridDim.x = nz <= 8
    float acc[4][4] = {};
    for (int j = z; j <= s; j += 8)
        tile64dsum<false>(Qall, 2048, uB, mt*64, j*64, j*64 + 64, acc, sA, sB);
    store_tile(hB + (size_t)z*131072, 64, mt*64, acc);
}

// Z'(rows w) = (sum_z Cp[z]) - hB[0] - ... - hB[nz-1]; Gp[w] = Z'^T Z' (f64)
__global__ __launch_bounds__(256)
void lz_finZs(float* __restrict__ Z, const float* __restrict__ Cp,
              const float* __restrict__ hB, int nz, double* __restrict__ Gp)
{
    __shared__ float zb[64][65];
    int w = blockIdx.x, tid = threadIdx.x;
    for (int idx = tid; idx < 4096; idx += 256) {
        size_t o = (size_t)w*4096 + idx;
        float v = 0.f;
        #pragma unroll
        for (int z = 0; z < 8; ++z) v += Cp[(size_t)z*131072 + o];
        for (int z = 0; z < nz; ++z) v -= hB[(size_t)z*131072 + o];
        Z[o] = v;
        zb[idx >> 6][idx & 63] = v;
    }
    __syncthreads();
    int tx = tid & 15, ty = tid >> 4;
    double acc[4][4] = {};
    for (int r = 0; r < 64; ++r) {
        float av[4], bv[4];
        #pragma unroll
        for (int q = 0; q < 4; ++q) { av[q] = zb[r][ty*4 + q]; bv[q] = zb[r][tx*4 + q]; }
        #pragma unroll
        for (int i = 0; i < 4; ++i)
            #pragma unroll
            for (int j = 0; j < 4; ++j)
                acc[i][j] += (double)av[i] * (double)bv[j];
    }
    #pragma unroll
    for (int i = 0; i < 4; ++i)
        #pragma unroll
        for (int j = 0; j < 4; ++j)
            Gp[(size_t)w*4096 + (size_t)(ty*4 + i)*64 + tx*4 + j] = acc[i][j];
}

// f64 Cholesky of G = sum Gp (32 partials); Bb_s = R (f32); RinvF = R^{-1} (f32);
// also stashes Ab[s] = sum_z uB[z] rows [64s,64s+64)  (the A_s diagonal block)
__global__ __launch_bounds__(256)
void lz_chols(const double* __restrict__ Gp, const float* __restrict__ uB, int s,
              float* __restrict__ RinvF, float* __restrict__ BbS, float* __restrict__ AbS)
{
    __shared__ double G[64][65];
    __shared__ double Xs[64][65];
    __shared__ double lv[64];
    int tid = threadIdx.x;
    for (int idx = tid; idx < 4096; idx += 256) {
        float v = 0.f;
        #pragma unroll
        for (int z = 0; z < 8; ++z) v += uB[(size_t)z*131072 + (size_t)s*4096 + idx];
        AbS[idx] = v;
        double g = 0.0;
        for (int z = 0; z < 32; ++z) g += Gp[(size_t)z*4096 + idx];
        G[idx>>6][idx&63] = g;
    }
    __syncthreads();
    for (int k = 0; k < 64; ++k) {
        if (tid < 64) {
            double rkk = sqrt(fmax(G[k][k], 1e-40));
            lv[tid] = (tid == k) ? rkk : ((tid > k) ? G[k][tid]/rkk : 0.0);
        }
        __syncthreads();
        if (tid < 64 && tid >= k) G[k][tid] = lv[tid];
        for (int idx = tid; idx < 4096; idx += 256) {
            int i = idx>>6, j = idx&63;
            if (i > k && j >= i) G[i][j] -= lv[i]*lv[j];
        }
        __syncthreads();
    }
    for (int idx = tid; idx < 4096; idx += 256) {
        int i = idx>>6, j = idx&63;
        BbS[idx] = (j >= i) ? (float)G[i][j] : 0.f;
        Xs[i][j] = 0.0;
    }
    __syncthreads();
    if (tid < 64) {
        int j = tid;
        for (int i = j; i >= 0; --i) {
            double s2 = (i == j) ? 1.0 : 0.0;
            for (int k2 = i + 1; k2 <= j; ++k2) s2 -= G[i][k2]*Xs[k2][j];
            Xs[i][j] = s2 / G[i][i];
        }
    }
    __syncthreads();
    for (int idx = tid; idx < 4096; idx += 256)
        RinvF[idx] = (float)Xs[idx>>6][idx&63];
}

// final step: only the A-block stash is needed
__global__ void lz_abstash(const float* __restrict__ uB, float* __restrict__ AbS, int s) {
    int idx = blockIdx.x*256 + threadIdx.x;  // grid 16
    float v = 0.f;
    #pragma unroll
    for (int z = 0; z < 8; ++z) v += uB[(size_t)z*131072 + (size_t)s*4096 + idx];
    AbS[idx] = v;
}

// Qnext(rows w) = Z'(rows w) * Rinv
__global__ __launch_bounds__(256)
void lz_apply(const float* __restrict__ Z, const float* __restrict__ Rinv, float* __restrict__ Qn)
{
    __shared__ float sA[2][16][68], sB[2][16][68];
    int w = blockIdx.x;
    float acc[4][4] = {};
    tile64d<false,false>(Z, 64, Rinv, 64, w*64, 0, 0, 64, acc, sA, sB);
    store_tile(Qn, 2048, w*64, acc);
}

// band[c*65+r] = T[c+r, c]
__global__ void assemble_band(const float* Ab, const float* Bb, float* band) {
    int idx = blockIdx.x*256 + threadIdx.x;
    if (idx >= 2048*65) return;
    int c = idx / 65, r = idx % 65;
    int row = c + r;
    float v = 0.f;
    if (row < 2048) {
        int j = c >> 6, q = c & 63, rr = q + r;
        if (rr <= 63) {
            const float* A = Ab + (size_t)j*4096;
            v = 0.5f*(A[rr*64 + q] + A[q*64 + rr]);
        } else if (j < 31) {
            int p = rr - 64;
            v = Bb[(size_t)j*4096 + p*64 + q];
        }
    }
    band[idx] = v;
}

// ---------------------------------------------------------------------------
// Pack helpers
// ---------------------------------------------------------------------------
__device__ __forceinline__
void pack_item(int idx, const float* __restrict__ src, const float* __restrict__ dv,
               ushort* __restrict__ Bh, ushort* __restrict__ Bl,
               ushort* __restrict__ Ch, ushort* __restrict__ Cl)
{
    int l = idx & 63, t = idx >> 6;
    int nb = t & 31, kc = t >> 5;
    int col = nb*16 + (l & 15);
    int k0 = kc*32 + ((l >> 4) << 3);
    ushort h8[8], l8[8], sh8[8], sl8[8];
    #pragma unroll
    for (int j = 0; j < 8; ++j) {
        int k = k0 + j;
        float v = src[(size_t)k*512 + col];
        ushort hb = bf16_rne(v);
        h8[j] = hb; l8[j] = bf16_rne(v - bf16_tof(hb));
        if (Ch) {
            float t2 = v * (1.0f / sqrtf(dv[k] + 1e-10f));
            ushort hb2 = bf16_rne(t2);
            sh8[j] = hb2; sl8[j] = bf16_rne(t2 - bf16_tof(hb2));
        }
    }
    uint4 hv, lv;
    hv.x = (unsigned)h8[0] | ((unsigned)h8[1] << 16);
    hv.y = (unsigned)h8[2] | ((unsigned)h8[3] << 16);
    hv.z = (unsigned)h8[4] | ((unsigned)h8[5] << 16);
    hv.w = (unsigned)h8[6] | ((unsigned)h8[7] << 16);
    lv.x = (unsigned)l8[0] | ((unsigned)l8[1] << 16);
    lv.y = (unsigned)l8[2] | ((unsigned)l8[3] << 16);
    lv.z = (unsigned)l8[4] | ((unsigned)l8[5] << 16);
    lv.w = (unsigned)l8[6] | ((unsigned)l8[7] << 16);
    *(uint4*)(Bh + (size_t)idx*8) = hv;
    *(uint4*)(Bl + (size_t)idx*8) = lv;
    if (Ch) {
        uint4 shv, slv;
        shv.x = (unsigned)sh8[0] | ((unsigned)sh8[1] << 16);
        shv.y = (unsigned)sh8[2] | ((unsigned)sh8[3] << 16);
        shv.z = (unsigned)sh8[4] | ((unsigned)sh8[5] << 16);
        shv.w = (unsigned)sh8[6] | ((unsigned)sh8[7] << 16);
        slv.x = (unsigned)sl8[0] | ((unsigned)sl8[1] << 16);
        slv.y = (unsigned)sl8[2] | ((unsigned)sl8[3] << 16);
        slv.z = (unsigned)sl8[4] | ((unsigned)sl8[5] << 16);
        slv.w = (unsigned)sl8[6] | ((unsigned)sl8[7] << 16);
        *(uint4*)(Ch + (size_t)idx*8) = shv;
        *(uint4*)(Cl + (size_t)idx*8) = slv;
    }
}

__global__ void pack_both(const float* __restrict__ src, const float* __restrict__ dv,
                          ushort* __restrict__ Bh, ushort* __restrict__ Bl,
                          ushort* __restrict__ Ch, ushort* __restrict__ Cl)
{
    int idx = blockIdx.x*256 + threadIdx.x;
    if (idx < 131072) pack_item(idx, src, dv, Bh, Bl, Ch, Cl);
}

__global__ void pack_A_L(const float* __restrict__ src, int Kld, int MB,
                         ushort* __restrict__ Ah, ushort* __restrict__ Al, int total)
{
    int idx = blockIdx.x*256 + threadIdx.x;
    if (idx >= total) return;
    int l = idx & 63, t = idx >> 6;
    int mb = t % MB, kc = t / MB;
    int m = mb*16 + (l & 15);
    int k0 = kc*32 + ((l >> 4) << 3);
    const float* p = src + (size_t)m*Kld + k0;
    float4 a = *(const float4*)p, b = *(const float4*)(p + 4);
    float vv[8] = {a.x,a.y,a.z,a.w,b.x,b.y,b.z,b.w};
    ushort h8[8], l8[8];
    #pragma unroll
    for (int j = 0; j < 8; ++j) {
        ushort hb = bf16_rne(vv[j]);
        h8[j] = hb; l8[j] = bf16_rne(vv[j] - bf16_tof(hb));
    }
    uint4 hv, lv;
    hv.x = (unsigned)h8[0] | ((unsigned)h8[1] << 16);
    hv.y = (unsigned)h8[2] | ((unsigned)h8[3] << 16);
    hv.z = (unsigned)h8[4] | ((unsigned)h8[5] << 16);
    hv.w = (unsigned)h8[6] | ((unsigned)h8[7] << 16);
    lv.x = (unsigned)l8[0] | ((unsigned)l8[1] << 16);
    lv.y = (unsigned)l8[2] | ((unsigned)l8[3] << 16);
    lv.z = (unsigned)l8[4] | ((unsigned)l8[5] << 16);
    lv.w = (unsigned)l8[6] | ((unsigned)l8[7] << 16);
    *(uint4*)(Ah + (size_t)idx*8) = hv;
    *(uint4*)(Al + (size_t)idx*8) = lv;
}

__global__ void pack_A_T(const float* __restrict__ src, int Mld, int MB,
                         ushort* __restrict__ Ah, int total)
{
    int idx = blockIdx.x*256 + threadIdx.x;
    if (idx >= total) return;
    int l = idx & 63, t = idx >> 6;
    int mb = t % MB, kc = t / MB;
    int m = mb*16 + (l & 15);
    int k0 = kc*32 + ((l >> 4) << 3);
    ushort h8[8];
    #pragma unroll
    for (int j = 0; j < 8; ++j)
        h8[j] = bf16_rne(src[(size_t)(k0 + j)*Mld + m]);
    uint4 hv;
    hv.x = (unsigned)h8[0] | ((unsigned)h8[1] << 16);
    hv.y = (unsigned)h8[2] | ((unsigned)h8[3] << 16);
    hv.z = (unsigned)h8[4] | ((unsigned)h8[5] << 16);
    hv.w = (unsigned)h8[6] | ((unsigned)h8[7] << 16);
    *(uint4*)(Ah + (size_t)idx*8) = hv;
}

// ---------------------------------------------------------------------------
// MFMA split-bf16 dual GEMM task
// ---------------------------------------------------------------------------
__device__ __forceinline__
void mfma_task(int t, const ushort* __restrict__ Lph, const ushort* __restrict__ Lpl,
               const ushort* __restrict__ Bh, const ushort* __restrict__ Bl,
               const ushort* __restrict__ Htp,
               const ushort* __restrict__ Bqh, const ushort* __restrict__ Bql,
               float* __restrict__ U, float* __restrict__ ME,
               ushort (*lA)[4096], ushort (*lB)[4096])
{
    const bool isU = (t < 64);
    const ushort* Ah = isU ? Lph : Htp;
    const ushort* Al = isU ? Lpl : nullptr;
    const ushort* Xh = isU ? Bh : Bqh;
    const ushort* Xl = isU ? Bl : Bql;
    float* C = isU ? U : ME;
    const int MB = isU ? 128 : 64;
    const int tmb = (isU ? (t >> 2) : ((t - 64) >> 2)) * 8;
    const int tnb = (t & 3) * 8;
    const int KC = 64;
    const int tid = threadIdx.x;
    const int lane = tid & 63, wave = tid >> 6;
    const int wr = wave >> 1, wc = wave & 1;

    f32x4 acc[4][4];
    #pragma unroll
    for (int i = 0; i < 4; ++i)
        #pragma unroll
        for (int j = 0; j < 4; ++j) acc[i][j] = (f32x4){0.f,0.f,0.f,0.f};

    uint4 rAh[2], rAl[2], rBh[2], rBl[2];
    auto loadregs = [&](int kc) {
        const uint4* pa = (const uint4*)(Ah + ((size_t)kc*MB + tmb)*512);
        rAh[0] = pa[tid]; rAh[1] = pa[tid + 256];
        if (Al) {
            const uint4* pl = (const uint4*)(Al + ((size_t)kc*MB + tmb)*512);
            rAl[0] = pl[tid]; rAl[1] = pl[tid + 256];
        }
        const uint4* pb = (const uint4*)(Xh + ((size_t)kc*32 + tnb)*512);
        rBh[0] = pb[tid]; rBh[1] = pb[tid + 256];
        const uint4* pc = (const uint4*)(Xl + ((size_t)kc*32 + tnb)*512);
        rBl[0] = pc[tid]; rBl[1] = pc[tid + 256];
    };

    loadregs(0);
    for (int kc = 0; kc < KC; ++kc) {
        __syncthreads();
        *(uint4*)&lA[0][tid*8]       = rAh[0];
        *(uint4*)&lA[0][(tid+256)*8] = rAh[1];
        if (Al) {
            *(uint4*)&lA[1][tid*8]       = rAl[0];
            *(uint4*)&lA[1][(tid+256)*8] = rAl[1];
        }
        *(uint4*)&lB[0][tid*8]       = rBh[0];
        *(uint4*)&lB[0][(tid+256)*8] = rBh[1];
        *(uint4*)&lB[1][tid*8]       = rBl[0];
        *(uint4*)&lB[1][(tid+256)*8] = rBl[1];
        if (kc + 1 < KC) loadregs(kc + 1);
        __syncthreads();

        short8 a_h[4], a_l[4], b_h[4], b_l[4];
        #pragma unroll
        for (int i = 0; i < 4; ++i) {
            a_h[i] = *(const short8*)&lA[0][(((wr*4 + i)*64) + lane)*8];
            if (Al) a_l[i] = *(const short8*)&lA[1][(((wr*4 + i)*64) + lane)*8];
        }
        #pragma unroll
        for (int j = 0; j < 4; ++j) {
            b_h[j] = *(const short8*)&lB[0][(((wc*4 + j)*64) + lane)*8];
            b_l[j] = *(const short8*)&lB[1][(((wc*4 + j)*64) + lane)*8];
        }
        #pragma unroll
        for (int i = 0; i < 4; ++i)
            #pragma unroll
            for (int j = 0; j < 4; ++j) {
                acc[i][j] = __builtin_amdgcn_mfma_f32_16x16x32_bf16(a_h[i], b_h[j], acc[i][j], 0, 0, 0);
                acc[i][j] = __builtin_amdgcn_mfma_f32_16x16x32_bf16(a_h[i], b_l[j], acc[i][j], 0, 0, 0);
                if (Al)
                    acc[i][j] = __builtin_amdgcn_mfma_f32_16x16x32_bf16(a_l[i], b_h[j], acc[i][j], 0, 0, 0);
            }
    }
    const int r0 = tmb*16 + wr*64, c0 = tnb*16 + wc*64;
    #pragma unroll
    for (int i = 0; i < 4; ++i)
        #pragma unroll
        for (int j = 0; j < 4; ++j) {
            int row = r0 + i*16 + ((lane >> 4) << 2);
            int col = c0 + j*16 + (lane & 15);
            #pragma unroll
            for (int r = 0; r < 4; ++r)
                C[(size_t)(row + r)*512 + col] = acc[i][j][r];
        }
}

__global__ __launch_bounds__(256, 2)
void mgemm_dual(const ushort* __restrict__ Lph, const ushort* __restrict__ Lpl,
                const ushort* __restrict__ Bh, const ushort* __restrict__ Bl,
                const ushort* __restrict__ Htp,
                const ushort* __restrict__ Bqh, const ushort* __restrict__ Bql,
                float* __restrict__ U, float* __restrict__ ME)
{
    __shared__ ushort lA[2][4096];
    __shared__ ushort lB[2][4096];
    int t = blockIdx.y * 4 + blockIdx.x;
    mfma_task(t, Lph, Lpl, Bh, Bl, Htp, Bqh, Bql, U, ME, lA, lB);
}

// ---------------------------------------------------------------------------
// Persistent MLP: layers 0..8, 4 barriers/layer. (round-7 version)
// ---------------------------------------------------------------------------
__global__ __launch_bounds__(256, 1)
void mlp_persist(float* __restrict__ u, float* __restrict__ h,
                 const float* __restrict__ Wf, const float* __restrict__ Wm,
                 const ushort* __restrict__ Lph, const ushort* __restrict__ Lpl,
                 const ushort* __restrict__ Htp,
                 ushort* __restrict__ bpkh, ushort* __restrict__ bpkl,
                 ushort* __restrict__ bqh, ushort* __restrict__ bql,
                 const float* __restrict__ H, const float* __restrict__ dv,
                 const float* __restrict__ de,
                 float* __restrict__ mEb, float* __restrict__ srow,
                 float* __restrict__ qpart,
                 float* __restrict__ parts512, float* __restrict__ parts16,
                 float* __restrict__ outp, int* __restrict__ bar)
{
    const int w = blockIdx.x, tid = threadIdx.x;
    __shared__ char smem[35072];
    __shared__ float red4[4];
    float (*sA)[68] = (float(*)[68])smem;
    float (*sB)[68] = (float(*)[68])(smem + 4352);
    ushort (*lA)[4096] = (ushort(*)[4096])smem;
    ushort (*lB)[4096] = (ushort(*)[4096])(smem + 16384);
    int ep = 0;

    for (int k = 0; k < 9; ++k) {
        const float* W = (k == 0) ? Wf : Wm + (size_t)(k-1)*262144;
        if (w == 0 && k > 0 && tid < 64) {
            float s = parts512[tid] + parts512[tid+64] + parts512[tid+128] + parts512[tid+192];
            for (int o = 32; o; o >>= 1) s += __shfl_down(s, o, 64);
            float x = (tid < 16) ? parts16[tid] : 0.f;
            for (int o = 32; o; o >>= 1) x += __shfl_down(x, o, 64);
            if (tid == 0) { outp[81920 + k - 1] = s; outp[81930 + k - 1] = x; }
        }
        {
            int mt = w >> 3, nt = w & 7;
            float acc[4][4] = {};
            tile64g<false,true>(u, 512, W, 512, mt*64, nt*64, 0, 512, acc, sA, sB);
            int tx = tid & 15, ty = tid >> 4;
            #pragma unroll
            for (int i = 0; i < 4; ++i)
                #pragma unroll
                for (int j = 0; j < 4; ++j)
                    h[(size_t)(mt*64 + ty*4 + i)*512 + nt*64 + tx*4 + j] = fmaxf(acc[i][j], 0.f);
        }
        pbar(bar, ++ep, w, 256);
        for (int it = w*256 + tid; it < 131072; it += 65536)
            pack_item(it, h, dv, bpkh, bpkl, bqh, bql);
        {
            int lane = tid & 63;
            #pragma unroll
            for (int g = 0; g < 2; ++g) {
                int row = w*8 + g*4 + (tid >> 6);
                float rs = 1.0f / sqrtf(dv[row] + 1e-10f);
                float ss = 0.f;
                for (int f = lane; f < 512; f += 64) {
                    float t2 = h[(size_t)row*512 + f] * rs;
                    ss += t2*t2;
                }
                for (int o = 32; o; o >>= 1) ss += __shfl_down(ss, o, 64);
                if (lane == 0) srow[row] = ss;
            }
        }
        pbar(bar, ++ep, w, 256);
        if (w < 96) {
            mfma_task(w, Lph, Lpl, bpkh, bpkl, Htp, bqh, bql, u, mEb, lA, lB);
        } else if (w < 128) {
            int task = w - 96;
            int e = (task & 3)*256 + tid;
            int zc = task >> 2;
            float s = 0.f;
            for (int n = zc*256; n < zc*256 + 256; ++n) s += H[(size_t)n*1024 + e] * srow[n];
            qpart[(size_t)zc*1024 + e] = s;
        }
        pbar(bar, ++ep, w, 256);
        if (w < 16) {
            int wave = tid >> 6, lane = tid & 63;
            float acc = 0.f;
            for (int t2 = 0; t2 < 16; ++t2) {
                int e = w*64 + wave*16 + t2;
                float me2 = 0.f;
                for (int f = lane; f < 512; f += 64) { float v = mEb[(size_t)e*512 + f]; me2 += v*v; }
                for (int o = 32; o; o >>= 1) me2 += __shfl_down(me2, o, 64);
                if (lane == 0) {
                    float q = 0.f;
                    for (int z = 0; z < 8; ++z) q += qpart[(size_t)z*1024 + e];
                    acc += (de[e]*q - me2) / (de[e] + 1e-10f);
                }
            }
            if (lane == 0) red4[wave] = acc;
            __syncthreads();
            if (tid == 0) parts16[w] = red4[0]+red4[1]+red4[2]+red4[3];
            __syncthreads();
        }
        {
            int lane = tid & 63;
            float dd = 0.f;
            #pragma unroll
            for (int g = 0; g < 2; ++g) {
                int row = w*8 + g*4 + (tid >> 6);
                for (int f = lane; f < 512; f += 64)
                    dd += h[(size_t)row*512 + f] * u[(size_t)row*512 + f];
            }
            for (int o = 32; o; o >>= 1) dd += __shfl_down(dd, o, 64);
            __syncthreads();
            if (lane == 0) red4[tid >> 6] = dd;
            __syncthreads();
            if (tid == 0) parts512[w] = red4[0]+red4[1]+red4[2]+red4[3];
        }
        pbar(bar, ++ep, w, 256);
    }
    if (w == 0 && tid < 64) {
        float s = parts512[tid] + parts512[tid+64] + parts512[tid+128] + parts512[tid+192];
        for (int o = 32; o; o >>= 1) s += __shfl_down(s, o, 64);
        float x = (tid < 16) ? parts16[tid] : 0.f;
        for (int o = 32; o; o >>= 1) x += __shfl_down(x, o, 64);
        if (tid == 0) { outp[81928] = s; outp[81938] = x; }
    }
}

// ---------------------------------------------------------------------------
// 64x64 f32 GEMM (layer 9 + small shapes), split-K
// ---------------------------------------------------------------------------
template<bool TA, bool TB>
__global__ __launch_bounds__(256)
void gemm_f32(const float* A, int lda, const float* B, int ldb,
              float* C, int ldc, float* Cpart,
              int M, int N, int K, float alpha, float beta, int relu)
{
    const int S = (int)gridDim.z, z = (int)blockIdx.z;
    const int kchunk = (K + S - 1) / S;
    const int k0 = z * kchunk;
    const int k1 = (K < k0 + kchunk) ? K : (k0 + kchunk);
    const int bm = blockIdx.y * 64, bn = blockIdx.x * 64;
    __shared__ float As[16][68];
    __shared__ float Bs[16][68];
    const int tid = threadIdx.x;
    const int tx = tid & 15, ty = tid >> 4;
    float acc[4][4] = {};
    for (int kk = k0; kk < k1; kk += 16) {
        for (int i = tid; i < 1024; i += 256) {
            int m, k;
            if (TA) { m = i & 63; k = i >> 6; } else { k = i & 15; m = i >> 4; }
            int gm = bm + m, gk = kk + k;
            float v = 0.f;
            if (gm < M && gk < k1) v = TA ? A[(size_t)gk*lda + gm] : A[(size_t)gm*lda + gk];
            As[k][m] = v;
        }
        for (int i = tid; i < 1024; i += 256) {
            int n, k;
            if (TB) { k = i & 15; n = i >> 4; } else { n = i & 63; k = i >> 6; }
            int gn = bn + n, gk = kk + k;
            float v = 0.f;
            if (gn < N && gk < k1) v = TB ? B[(size_t)gn*ldb + gk] : B[(size_t)gk*ldb + gn];
            Bs[k][n] = v;
        }
        __syncthreads();
        #pragma unroll
        for (int k = 0; k < 16; ++k) {
            float4 ra4 = *reinterpret_cast<const float4*>(&As[k][ty*4]);
            float4 rb4 = *reinterpret_cast<const float4*>(&Bs[k][tx*4]);
            float ra[4] = {ra4.x, ra4.y, ra4.z, ra4.w};
            float rb[4] = {rb4.x, rb4.y, rb4.z, rb4.w};
            #pragma unroll
            for (int i = 0; i < 4; ++i)
                #pragma unroll
                for (int j = 0; j < 4; ++j)
                    acc[i][j] += ra[i] * rb[j];
        }
        __syncthreads();
    }
    if (S == 1) {
        #pragma unroll
        for (int i = 0; i < 4; ++i) {
            int gm = bm + ty*4 + i;
            if (gm >= M) continue;
            #pragma unroll
            for (int j = 0; j < 4; ++j) {
                int gn = bn + tx*4 + j;
                if (gn >= N) continue;
                float v = alpha * acc[i][j];
                if (beta != 0.f) v += beta * C[(size_t)gm*ldc + gn];
                if (relu) v = fmaxf(v, 0.f);
                C[(size_t)gm*ldc + gn] = v;
            }
        }
    } else {
        float* P = Cpart + (size_t)z * M * N;
        #pragma unroll
        for (int i = 0; i < 4; ++i) {
            int gm = bm + ty*4 + i;
            if (gm >= M) continue;
            #pragma unroll
            for (int j = 0; j < 4; ++j) {
                int gn = bn + tx*4 + j;
                if (gn >= N) continue;
                P[(size_t)gm*N + gn] = alpha * acc[i][j];
            }
        }
    }
}

__global__ void reduce_parts(const float* Cpart, float* C, int M, int N, int ldc,
                             int S, float beta, int relu)
{
    int total = M * N;
    for (int idx = blockIdx.x*256 + threadIdx.x; idx < total; idx += gridDim.x*256) {
        float s = 0.f;
        for (int z = 0; z < S; ++z) s += Cpart[(size_t)z*total + idx];
        int mm = idx / N, nn = idx % N;
        float v = s;
        if (beta != 0.f) v += beta * C[(size_t)mm*ldc + nn];
        if (relu) v = fmaxf(v, 0.f);
        C[(size_t)mm*ldc + nn] = v;
    }
}

// ---------------------------------------------------------------------------
// Setup / layer-9 utility kernels
// ---------------------------------------------------------------------------
__global__ void row_deg(const float* H, float* dv) {
    int row = blockIdx.x*4 + (threadIdx.x >> 6);
    int lane = threadIdx.x & 63;
    if (row >= 2048) return;
    float s = 0.f;
    for (int e = lane; e < 1024; e += 64) s += H[(size_t)row*1024 + e];
    for (int o = 32; o; o >>= 1) s += __shfl_down(s, o, 64);
    if (lane == 0) dv[row] = s;
}

__global__ void coldot_part(const float* H, const float* w, float* part) {
    int e = blockIdx.x*256 + threadIdx.x;
    int zc = blockIdx.y;
    float s = 0.f;
    if (w) {
        for (int n = zc*256; n < zc*256 + 256; ++n) s += H[(size_t)n*1024 + e] * w[n];
    } else {
        for (int n = zc*256; n < zc*256 + 256; ++n) s += H[(size_t)n*1024 + e];
    }
    part[(size_t)zc*1024 + e] = s;
}
__global__ void coldot_fin(const float* part, float* outp) {
    int e = blockIdx.x*256 + threadIdx.x;
    float s = 0.f;
    for (int z = 0; z < 8; ++z) s += part[(size_t)z*1024 + e];
    outp[e] = s;
}

__global__ void dotsrow(const float* h, const float* u, int F, const float* dv,
                        float* srow, float* yout, float* parts)
{
    int row = blockIdx.x*4 + (threadIdx.x >> 6);
    int lane = threadIdx.x & 63;
    __shared__ float a4[4];
    float rs = 1.0f / sqrtf(dv[row] + 1e-10f);
    float ss = 0.f, dd = 0.f;
    for (int f = lane; f < F; f += 64) {
        float hv = h[(size_t)row*F + f];
        float t = hv * rs;
        if (yout) yout[(size_t)row*F + f] = t;
        ss += t*t;
        dd += hv * u[(size_t)row*F + f];
    }
    for (int o = 32; o; o >>= 1) { ss += __shfl_down(ss, o, 64); dd += __shfl_down(dd, o, 64); }
    if (lane == 0) { srow[row] = ss; a4[threadIdx.x >> 6] = dd; }
    __syncthreads();
    if (threadIdx.x == 0) parts[blockIdx.x] = a4[0]+a4[1]+a4[2]+a4[3];
}

__global__ void edge_energy(const float* m, int F, const float* de, const float* qpart,
                            float* partials) {
    int wave = threadIdx.x >> 6, lane = threadIdx.x & 63;
    __shared__ float acc4[4];
    float acc = 0.f;
    for (int t = 0; t < 16; ++t) {
        int e = blockIdx.x*64 + wave*16 + t;
        float me2 = 0.f;
        for (int f = lane; f < F; f += 64) { float v = m[(size_t)e*F + f]; me2 += v*v; }
        for (int o = 32; o; o >>= 1) me2 += __shfl_down(me2, o, 64);
        if (lane == 0) {
            float q = 0.f;
            for (int z = 0; z < 8; ++z) q += qpart[(size_t)z*1024 + e];
            acc += (de[e]*q - me2) / (de[e] + 1e-10f);
        }
    }
    if (lane == 0) acc4[wave] = acc;
    __syncthreads();
    if (threadIdx.x == 0) partials[blockIdx.x] = acc4[0]+acc4[1]+acc4[2]+acc4[3];
}

__global__ void finalize2(const float* p512, const float* p16, float* oe, float* ox) {
    __shared__ float red[256];
    int tid = threadIdx.x;
    red[tid] = p512[tid] + p512[tid + 256];
    __syncthreads();
    for (int st = 128; st; st >>= 1) { if (tid < st) red[tid] += red[tid+st]; __syncthreads(); }
    if (tid == 0) *oe = red[0];
    __syncthreads();
    red[tid] = (tid < 16) ? p16[tid] : 0.f;
    __syncthreads();
    for (int st = 128; st; st >>= 1) { if (tid < st) red[tid] += red[tid+st]; __syncthreads(); }
    if (tid == 0) *ox = red[0];
}

__global__ void logsoftmax(const float* xf, float* outp) {
    __shared__ float red[256];
    int c = blockIdx.x, tid = threadIdx.x;
    float mx = -3.0e38f;
    for (int n = tid; n < 2048; n += 256) mx = fmaxf(mx, xf[(size_t)n*40 + c]);
    red[tid] = mx; __syncthreads();
    for (int st = 128; st; st >>= 1) { if (tid < st) red[tid] = fmaxf(red[tid], red[tid+st]); __syncthreads(); }
    mx = red[0]; __syncthreads();
    float s = 0.f;
    for (int n = tid; n < 2048; n += 256) s += expf(xf[(size_t)n*40 + c] - mx);
    red[tid] = s; __syncthreads();
    for (int st = 128; st; st >>= 1) { if (tid < st) red[tid] += red[tid+st]; __syncthreads(); }
    float lse = mx + logf(red[0]);
    for (int n = tid; n < 2048; n += 256) outp[(size_t)n*40 + c] = xf[(size_t)n*40 + c] - lse;
}

// ---------------------------------------------------------------------------
// Sturm count via band LDL^T — ONE barrier per column (round-11 version).
// ---------------------------------------------------------------------------
__global__ __launch_bounds__(256)
void band_count(const float* __restrict__ band, const double* __restrict__ shifts,
                int* __restrict__ counts)
{
    __shared__ double win[66][66];
    const int tid = threadIdx.x;
    const double sigma = shifts[blockIdx.x];
    int ei[9], ej[9];
    {
        int i = 1, S = 0;
        #pragma unroll
        for (int k = 0; k < 9; ++k) {
            int T = tid + k*256;
            if (T < 2080) {
                while (S + (65 - i) <= T) { S += 65 - i; ++i; }
                ei[k] = i; ej[k] = i + (T - S);
            } else { ei[k] = 0; ej[k] = 0; }
        }
    }
    for (int idx = tid; idx < 65*65; idx += 256) {
        int c0 = idx / 65, r = idx % 65;
        win[c0][r] = (double)band[c0*65 + r] - (r == 0 ? sigma : 0.0);
    }
    __syncthreads();
    int cnt = 0;
    for (int c = 0; c < 2048; ++c) {
        const int p = c % 66;
        double d = win[p][0];
        if (fabs(d) < 1e-100) d = (d < 0 ? -1e-100 : 1e-100);
        if (d < 0) cnt++;
        double inv = 1.0 / d;
        #pragma unroll
        for (int k = 0; k < 9; ++k) {
            int i = ei[k];
            if (i) {
                int j = ej[k];
                int r2 = p + i; if (r2 >= 66) r2 -= 66;
                win[r2][j - i] -= win[p][i] * inv * win[p][j];
            }
        }
        int cn = c + 65;
        int slot = p + 65; if (slot >= 66) slot -= 66;
        if (tid < 65)
            win[slot][tid] = (cn < 2048)
                ? ((double)band[(size_t)cn*65 + tid] - (tid == 0 ? sigma : 0.0)) : 0.0;
        __syncthreads();
    }
    if (tid == 0) counts[blockIdx.x] = cnt;
}

__global__ void bisect(double* shifts, const int* counts, double* st, float* gap_out, int mode) {
    if (threadIdx.x != 0) return;
    if (mode == 0) {
        shifts[0] = 1e-10;
        double l0 = log(1e-6), l1 = log(0.5);
        for (int i = 1; i < NSHIFT; ++i) shifts[i] = exp(l0 + (l1 - l0)*(i - 1)/(double)(NSHIFT - 2));
        return;
    }
    if (mode == 1) {
        int n0 = counts[0];
        double lo = shifts[NSHIFT-1], hi = 1.5;
        for (int i = 1; i < NSHIFT; ++i) if (counts[i] > n0) { lo = shifts[i-1]; hi = shifts[i]; break; }
        st[0] = lo; st[1] = hi; st[2] = (double)n0;
        for (int i = 0; i < NSHIFT; ++i) shifts[i] = lo + (hi - lo)*(i + 1)/(double)(NSHIFT + 1);
        return;
    }
    int n0 = (int)st[2];
    double lo = st[0], hi = st[1];
    double nlo = shifts[NSHIFT-1], nhi = hi;
    for (int i = 0; i < NSHIFT; ++i) if (counts[i] > n0) { nhi = shifts[i]; nlo = (i == 0) ? lo : shifts[i-1]; break; }
    *gap_out = (float)(0.5*(nlo + nhi));
}

// ---------------------------------------------------------------------------
// Spectral norms
// ---------------------------------------------------------------------------
__global__ __launch_bounds__(256)
void gram9(const float* __restrict__ Wf, const float* __restrict__ Wm, float* __restrict__ sG)
{
    int mi = blockIdx.z;
    const float* W = (mi == 0) ? Wf : Wm + (size_t)(mi-1)*262144;
    __shared__ float sA[16][68], sB[16][68];
    int tid = threadIdx.x, tx = tid & 15, ty = tid >> 4;
    int bm = blockIdx.y*64, bn = blockIdx.x*64;
    float acc[4][4] = {};
    for (int kk = 0; kk < 512; kk += 16) {
        __syncthreads();
        for (int i = tid; i < 1024; i += 256) { int m = i&63, k = i>>6; sA[k][m] = W[(size_t)(kk+k)*512 + bm+m]; }
        for (int i = tid; i < 1024; i += 256) { int n = i&63, k = i>>6; sB[k][n] = W[(size_t)(kk+k)*512 + bn+n]; }
        __syncthreads();
        #pragma unroll
        for (int k = 0; k < 16; ++k) {
            float4 a4 = *(const float4*)&sA[k][ty*4];
            float4 b4 = *(const float4*)&sB[k][tx*4];
            float av[4]={a4.x,a4.y,a4.z,a4.w}, bv[4]={b4.x,b4.y,b4.z,b4.w};
            #pragma unroll
            for (int i = 0; i < 4; ++i)
                #pragma unroll
                for (int j = 0; j < 4; ++j) acc[i][j] += av[i]*bv[j];
        }
    }
    float* C = sG + (size_t)mi*262144;
    #pragma unroll
    for (int i = 0; i < 4; ++i)
        #pragma unroll
        for (int j = 0; j < 4; ++j)
            C[(size_t)(bm + ty*4 + i)*512 + bn + tx*4 + j] = acc[i][j];
}

__global__ __launch_bounds__(256)
void snorm_lanczos(const float* Gall, const float* Wl, float* outp) {
    int w = blockIdx.x, tid = threadIdx.x;
    int n = (w < 9) ? 512 : 40;
    const float* G = Gall + (size_t)w*262144;
    __shared__ float g40[1600];
    __shared__ float v[512], vp[512], wv[512], red[256];
    __shared__ float al[32], be[32];
    if (w == 9) {
        for (int p = tid; p < 1600; p += 256) {
            int i = p / 40, j = p % 40;
            float s = 0.f;
            for (int k2 = 0; k2 < 512; ++k2) s += Wl[(size_t)i*512 + k2]*Wl[(size_t)j*512 + k2];
            g40[p] = s;
        }
        __syncthreads();
    }
    float inv0 = 1.f / sqrtf((float)n);
    for (int i = tid; i < n; i += 256) { v[i] = inv0; vp[i] = 0.f; }
    __syncthreads();
    float beta_prev = 0.f;
    for (int s = 0; s < 32; ++s) {
        for (int r = tid; r < n; r += 256) {
            float sum = 0.f;
            if (w < 9) { const float* row = G + (size_t)r*512; for (int k2 = 0; k2 < 512; ++k2) sum += row[k2]*v[k2]; }
            else       { const float* row = &g40[r*40];        for (int k2 = 0; k2 < 40;  ++k2) sum += row[k2]*v[k2]; }
            wv[r] = sum;
        }
        __syncthreads();
        float p = 0.f;
        for (int i = tid; i < n; i += 256) p += v[i]*wv[i];
        red[tid] = p; __syncthreads();
        for (int st = 128; st; st >>= 1) { if (tid < st) red[tid] += red[tid+st]; __syncthreads(); }
        float alpha = red[0]; __syncthreads();
        for (int i = tid; i < n; i += 256) wv[i] -= alpha*v[i] + beta_prev*vp[i];
        __syncthreads();
        p = 0.f;
        for (int i = tid; i < n; i += 256) p += wv[i]*wv[i];
        red[tid] = p; __syncthreads();
        for (int st = 128; st; st >>= 1) { if (tid < st) red[tid] += red[tid+st]; __syncthreads(); }
        float beta = sqrtf(fmaxf(red[0], 0.f)); __syncthreads();
        if (tid == 0) { al[s] = alpha; be[s] = beta; }
        float ib = 1.f / fmaxf(beta, 1e-20f);
        for (int i = tid; i < n; i += 256) { float t = v[i]; vp[i] = t; v[i] = wv[i]*ib; }
        beta_prev = beta;
        __syncthreads();
    }
    if (tid == 0) {
        float hi = 0.f;
        for (int s = 0; s < 32; ++s) {
            float g2 = al[s] + be[s] + (s ? be[s-1] : 0.f);
            hi = fmaxf(hi, g2);
        }
        float lo = 0.f;
        for (int it = 0; it < 48; ++it) {
            float mid = 0.5f*(lo + hi);
            float d = al[0] - mid; int c2 = (d < 0.f);
            for (int s = 1; s < 32; ++s) {
                float dp = d;
                if (fabsf(dp) < 1e-25f) dp = (dp < 0.f) ? -1e-25f : 1e-25f;
                d = (al[s] - mid) - be[s-1]*be[s-1]/dp;
                c2 += (d < 0.f);
            }
            if (c2 == 32) hi = mid; else lo = mid;
        }
        outp[w] = sqrtf(fmaxf(0.5f*(lo + hi), 0.f));
    }
}

// ---------------------------------------------------------------------------
// Host driver
// ---------------------------------------------------------------------------
static void gemm64(hipStream_t st, int ta, int tb, int M, int N, int K,
                   const float* A, int lda, const float* B, int ldb,
                   float* C, int ldc, float alpha, float beta, int relu,
                   float* Cpart, int S)
{
    dim3 grid((unsigned)((N + 63)/64), (unsigned)((M + 63)/64), (unsigned)S);
    if (!ta && !tb)      gemm_f32<false,false><<<grid,256,0,st>>>(A,lda,B,ldb,C,ldc,Cpart,M,N,K,alpha,beta,relu);
    else if (!ta && tb)  gemm_f32<false,true ><<<grid,256,0,st>>>(A,lda,B,ldb,C,ldc,Cpart,M,N,K,alpha,beta,relu);
    else if (ta && !tb)  gemm_f32<true ,false><<<grid,256,0,st>>>(A,lda,B,ldb,C,ldc,Cpart,M,N,K,alpha,beta,relu);
    else                 gemm_f32<true ,true ><<<grid,256,0,st>>>(A,lda,B,ldb,C,ldc,Cpart,M,N,K,alpha,beta,relu);
    if (S > 1) {
        int total = M * N;
        int g = (total + 255)/256; if (g > 2048) g = 2048;
        reduce_parts<<<g,256,0,st>>>(Cpart, C, M, N, ldc, S, beta, relu);
    }
}

extern "C" void kernel_launch(void* const* d_in, const int* in_sizes, int n_in,
                              void* d_out, int out_size, void* d_ws, size_t ws_size,
                              hipStream_t stream)
{
    (void)in_sizes; (void)n_in; (void)out_size; (void)ws_size;
    const float* X  = (const float*)d_in[0];
    const float* Lm = (const float*)d_in[1];
    const float* H  = (const float*)d_in[2];
    const float* Wf = (const float*)d_in[3];
    const float* Wm = (const float*)d_in[4];
    const float* Wl = (const float*)d_in[5];
    float* out = (float*)d_out;

    float* ws = (float*)d_ws;
    size_t off = 0;
    auto alloc = [&](size_t n) { float* p = ws + off; off += (n + 255) & ~(size_t)255; return p; };
    float* Lph_f  = alloc((size_t)2097152);   // L hi pack (ushort) | lancz Qall lo-half
    float* Lpl_f  = alloc((size_t)2097152);   // L lo pack          | Qall hi-half
    float* Htp_f  = alloc((size_t)1048576);   // H^T pack           | Z/Creo/Ab/Bb/band/Rinv
    float* bpkh_f = alloc((size_t)524288);    // B pack hi          | lancz Gp (f64)
    float* bpkl_f = alloc((size_t)524288);    // B pack lo
    float* h      = alloc((size_t)2048*512);  // MLP act | lancz QC partials
    float* u      = alloc((size_t)2048*512);  // MLP act | lancz QTZ partials
    float* mEb    = alloc((size_t)1024*512);  // mE | layer9: h9/y9/mE9
    float* Cpart  = alloc((size_t)1024*1024); // bq packs | split-K partials | lancz LQ partials
    float* dv     = alloc(2048);
    float* de     = alloc(1024);
    float* srow   = alloc(2048);
    float* qpart  = alloc(8*1024);
    float* parts512 = alloc(512);
    float* parts16  = alloc(256);
    double* shifts  = (double*)alloc(2*NSHIFT);
    double* bstate  = (double*)alloc(8);
    int* counts     = (int*)alloc(NSHIFT);
    int* barbase    = (int*)alloc(16384);

    ushort* Lph  = (ushort*)Lph_f;
    ushort* Lpl  = (ushort*)Lpl_f;
    ushort* Htp  = (ushort*)Htp_f;
    ushort* bpkh = (ushort*)bpkh_f;
    ushort* bpkl = (ushort*)bpkl_f;
    ushort* bqh  = (ushort*)Cpart;
    ushort* bql  = (ushort*)(Cpart + 524288);
    int* barM = barbase;
    // lancz-phase aliases (MLP packs/activations dead by then)
    float* Qall  = Lph_f;                // 2048*2048
    float* Z     = Htp_f;                // 2048*64
    float* Ab    = Htp_f + 262144;       // 32*64*64
    float* Bb    = Htp_f + 393216;       // 32*64*64
    float* band  = Htp_f + 524288;       // 2048*65
    float* Rinv  = Htp_f + 658432;       // 64*64
    double* GpD  = (double*)bpkh_f;      // 32*4096 f64 Gram partials
    float* sG    = Qall;                 // snorm Grams
    float* h9  = mEb;                    // 2048*40
    float* y9  = mEb + 131072;           // 2048*40
    float* mE9 = mEb + 262144;           // 1024*40

    // ---- setup ----
    init_misc<<<16,256,0,stream>>>(barbase);
    pack_A_L<<<2048,256,0,stream>>>(Lm, 2048, 128, Lph, Lpl, 524288);
    pack_A_T<<<1024,256,0,stream>>>(H, 1024, 64, Htp, 262144);
    row_deg<<<512,256,0,stream>>>(H, dv);
    coldot_part<<<dim3(4,8),256,0,stream>>>(H, nullptr, qpart);
    coldot_fin<<<4,256,0,stream>>>(qpart, de);

    // ---- u0 = L x ----
    pack_both<<<512,256,0,stream>>>(X, dv, bpkh, bpkl, nullptr, nullptr);
    mgemm_dual<<<dim3(4,16),256,0,stream>>>(Lph, Lpl, bpkh, bpkl, Htp, bqh, bql, u, mEb);

    // ---- layers 0..8: persistent kernel ----
    mlp_persist<<<256,256,0,stream>>>(u, h, Wf, Wm, Lph, Lpl, Htp,
                                      bpkh, bpkl, bqh, bql, H, dv, de,
                                      mEb, srow, qpart, parts512, parts16, out, barM);

    // ---- layer 9 (Fo=40, f32 vector path) ----
    gemm64(stream, 0,1, 2048,40,512, u,512, Wl,512, h9,40, 1.f,0.f,1, Cpart,8);
    gemm64(stream, 0,0, 2048,40,2048, Lm,2048, h9,40, u,40, 1.f,0.f,0, Cpart,8);
    dotsrow<<<512,256,0,stream>>>(h9, u, 40, dv, srow, y9, parts512);
    coldot_part<<<dim3(4,8),256,0,stream>>>(H, srow, qpart);
    gemm64(stream, 1,0, 1024,40,2048, H,1024, y9,40, mE9,40, 1.f,0.f,0, Cpart,8);
    edge_energy<<<16,256,0,stream>>>(mE9, 40, de, qpart, parts16);
    finalize2<<<1,256,0,stream>>>(parts512, parts16, out + 81929, out + 81939);
    logsoftmax<<<40,256,0,stream>>>(h9, out);

    // ---- block Lanczos: 6 graph-chained kernels/step ----
    init_q0<<<512,256,0,stream>>>(Qall);
    for (int s = 0; s < 32; ++s) {
        lz_LQ<<<dim3(8,32),256,0,stream>>>(Lm, Qall + 64*s, Cpart);
        lz_QTZs<<<dim3(8,(unsigned)(s+1)),256,0,stream>>>(Qall, Cpart, u);
        if (s == 31) { lz_abstash<<<16,256,0,stream>>>(u, Ab + (size_t)31*4096, 31); break; }
        int nz = (s + 1 < 8) ? s + 1 : 8;
        lz_QCs<<<dim3((unsigned)nz,32),256,0,stream>>>(Qall, u, h, s);
        lz_finZs<<<32,256,0,stream>>>(Z, Cpart, h, nz, GpD);
        lz_chols<<<1,256,0,stream>>>(GpD, u, s, Rinv, Bb + (size_t)s*4096, Ab + (size_t)s*4096);
        lz_apply<<<32,256,0,stream>>>(Z, Rinv, Qall + (size_t)64*(s+1));
    }
    assemble_band<<<520,256,0,stream>>>(Ab, Bb, band);

    // ---- Sturm bisection (2 rounds, single-barrier band_count) ----
    bisect<<<1,64,0,stream>>>(shifts, counts, bstate, out + 81950, 0);
    band_count<<<NSHIFT,256,0,stream>>>(band, shifts, counts);
    bisect<<<1,64,0,stream>>>(shifts, counts, bstate, out + 81950, 1);
    band_count<<<NSHIFT,256,0,stream>>>(band, shifts, counts);
    bisect<<<1,64,0,stream>>>(shifts, counts, bstate, out + 81950, 3);

    // ---- spectral norms ----
    gram9<<<dim3(8,8,9),256,0,stream>>>(Wf, Wm, sG);
    snorm_lanczos<<<10,256,0,stream>>>(sG, Wl, out + 81940);
}

// Round 13
// 15366.054 us; speedup vs baseline: 1.0476x; 1.0476x over previous
//
#include <hip/hip_runtime.h>
#include <math.h>

// N=2048 nodes, E=1024 edges, F=512 hidden, C=40 classes, 10 layers
// out: [81920 log_probs][10 energies][10 energies_exp][10 snorms][1 gap]

typedef __attribute__((ext_vector_type(8))) short short8;
typedef __attribute__((ext_vector_type(4))) float f32x4;

#define NSHIFT 256

__device__ inline ushort bf16_rne(float f) {
    unsigned int u = __float_as_uint(f);
    return (ushort)((u + 0x7FFFu + ((u >> 16) & 1u)) >> 16);
}
__device__ inline float bf16_tof(ushort h) {
    return __uint_as_float(((unsigned int)h) << 16);
}

// ---------------------------------------------------------------------------
// Contention-free grid barrier (used ONLY by mlp_persist; 27 barriers total)
// ---------------------------------------------------------------------------
__device__ __forceinline__ void pbar(int* bar, int e, int w, int nwg) {
    __syncthreads();
    if (threadIdx.x == 0) {
        __threadfence();
        __hip_atomic_store(bar + 16 + w*16, e, __ATOMIC_RELAXED, __HIP_MEMORY_SCOPE_AGENT);
    }
    if (w == 0) {
        if ((int)threadIdx.x < nwg) {
            while (__hip_atomic_load(bar + 16 + threadIdx.x*16, __ATOMIC_RELAXED,
                                     __HIP_MEMORY_SCOPE_AGENT) < e)
                __builtin_amdgcn_s_sleep(1);
        }
        __syncthreads();
        if (threadIdx.x == 0)
            __hip_atomic_store(bar, e, __ATOMIC_RELEASE, __HIP_MEMORY_SCOPE_AGENT);
    } else {
        if (threadIdx.x == 0) {
            while (__hip_atomic_load(bar, __ATOMIC_RELAXED, __HIP_MEMORY_SCOPE_AGENT) < e)
                __builtin_amdgcn_s_sleep(8);
        }
    }
    if (threadIdx.x == 0) __threadfence();
    __syncthreads();
}

__global__ void init_misc(int* bar) {
    for (int j = blockIdx.x*256 + threadIdx.x; j < 16384; j += gridDim.x*256) bar[j] = 0;
}

// ---------------------------------------------------------------------------
// 64x64 f32 tile MAC, single-buffered (mlp_persist uses this)
// ---------------------------------------------------------------------------
template<bool TA, bool TB>
__device__ __forceinline__
void tile64g(const float* __restrict__ A, int lda,
             const float* __restrict__ B, int ldb,
             int bm, int bn, int k0, int k1, float acc[4][4],
             float (*sA)[68], float (*sB)[68])
{
    const int tid = threadIdx.x;
    const int tx = tid & 15, ty = tid >> 4;
    for (int kk = k0; kk < k1; kk += 16) {
        __syncthreads();
        for (int i = tid; i < 1024; i += 256) {
            int m, k2;
            if (TA) { m = i & 63; k2 = i >> 6; } else { k2 = i & 15; m = i >> 4; }
            sA[k2][m] = TA ? A[(size_t)(kk + k2)*lda + bm + m]
                           : A[(size_t)(bm + m)*lda + kk + k2];
        }
        for (int i = tid; i < 1024; i += 256) {
            int n, k2;
            if (TB) { k2 = i & 15; n = i >> 4; } else { n = i & 63; k2 = i >> 6; }
            sB[k2][n] = TB ? B[(size_t)(bn + n)*ldb + kk + k2]
                           : B[(size_t)(kk + k2)*ldb + bn + n];
        }
        __syncthreads();
        #pragma unroll
        for (int k2 = 0; k2 < 16; ++k2) {
            float4 a4 = *(const float4*)&sA[k2][ty*4];
            float4 b4 = *(const float4*)&sB[k2][tx*4];
            float av[4] = {a4.x, a4.y, a4.z, a4.w};
            float bv[4] = {b4.x, b4.y, b4.z, b4.w};
            #pragma unroll
            for (int i2 = 0; i2 < 4; ++i2)
                #pragma unroll
                for (int j2 = 0; j2 < 4; ++j2)
                    acc[i2][j2] += av[i2] * bv[j2];
        }
    }
}

// ---------------------------------------------------------------------------
// 64x64 f32 tile MAC, DOUBLE-BUFFERED register prefetch.
// ---------------------------------------------------------------------------
template<bool TA, bool TB>
__device__ __forceinline__
void tile64d(const float* __restrict__ A, int lda,
             const float* __restrict__ B, int ldb,
             int bm, int bn, int k0, int k1, float acc[4][4],
             float (*sA)[16][68], float (*sB)[16][68])
{
    const int tid = threadIdx.x;
    const int tx = tid & 15, ty = tid >> 4;
    float ra[4], rb[4];
    auto ldregs = [&](int kk) {
        #pragma unroll
        for (int q = 0; q < 4; ++q) {
            int i = tid + q*256;
            if (TA) { int m = i & 63, k2 = i >> 6; ra[q] = A[(size_t)(kk + k2)*lda + bm + m]; }
            else    { int k2 = i & 15, m = i >> 4; ra[q] = A[(size_t)(bm + m)*lda + kk + k2]; }
            if (TB) { int k3 = i & 15, n = i >> 4; rb[q] = B[(size_t)(bn + n)*ldb + kk + k3]; }
            else    { int k3 = i >> 6, n = i & 63; rb[q] = B[(size_t)(kk + k3)*ldb + bn + n]; }
        }
    };
    auto stlds = [&](int buf) {
        #pragma unroll
        for (int q = 0; q < 4; ++q) {
            int i = tid + q*256;
            if (TA) { int m = i & 63, k2 = i >> 6; sA[buf][k2][m] = ra[q]; }
            else    { int k2 = i & 15, m = i >> 4; sA[buf][k2][m] = ra[q]; }
            if (TB) { int k3 = i & 15, n = i >> 4; sB[buf][k3][n] = rb[q]; }
            else    { int k3 = i >> 6, n = i & 63; sB[buf][k3][n] = rb[q]; }
        }
    };
    const int nit = (k1 - k0) >> 4;
    ldregs(k0);
    stlds(0);
    for (int it = 0; it < nit; ++it) {
        const int buf = it & 1;
        if (it + 1 < nit) ldregs(k0 + (it + 1)*16);
        __syncthreads();
        #pragma unroll
        for (int k2 = 0; k2 < 16; ++k2) {
            float4 a4 = *(const float4*)&sA[buf][k2][ty*4];
            float4 b4 = *(const float4*)&sB[buf][k2][tx*4];
            float av[4] = {a4.x, a4.y, a4.z, a4.w};
            float bv[4] = {b4.x, b4.y, b4.z, b4.w};
            #pragma unroll
            for (int i2 = 0; i2 < 4; ++i2)
                #pragma unroll
                for (int j2 = 0; j2 < 4; ++j2)
                    acc[i2][j2] += av[i2] * bv[j2];
        }
        if (it + 1 < nit) { __syncthreads(); stlds(buf ^ 1); }
    }
}

__device__ __forceinline__ void store_tile(float* C, int ldc, int bm, float acc[4][4]) {
    int tx = threadIdx.x & 15, ty = threadIdx.x >> 4;
    #pragma unroll
    for (int i = 0; i < 4; ++i)
        #pragma unroll
        for (int j = 0; j < 4; ++j)
            C[(size_t)(bm + ty*4 + i)*ldc + tx*4 + j] = acc[i][j];
}

// ---------------------------------------------------------------------------
// Block-Lanczos step kernels (round-11 structure: 8 graph-chained kernels/step)
// ---------------------------------------------------------------------------
__global__ void init_q0(float* Q) {
    int idx = blockIdx.x*256 + threadIdx.x;
    if (idx < 2048*64) {
        int n = idx >> 6, c = idx & 63;
        Q[(size_t)n*2048 + c] = (n == c) ? 1.f : 0.f;
    }
}

// Cp[z] = L(rows mt*64..)*Qs over K-chunk [z*256, z*256+256)
__global__ __launch_bounds__(256)
void lz_LQ(const float* __restrict__ Lm, const float* __restrict__ Qs, float* __restrict__ Cp)
{
    __shared__ float sA[2][16][68], sB[2][16][68];
    int z = blockIdx.x, mt = blockIdx.y;
    float acc[4][4] = {};
    tile64d<false,false>(Lm, 2048, Qs, 2048, mt*64, 0, z*256, z*256 + 256, acc, sA, sB);
    store_tile(Cp + (size_t)z*131072, 64, mt*64, acc);
}

__global__ void lz_sumZ(const float* __restrict__ Cp, float* __restrict__ Z)
{
    int idx = blockIdx.x*256 + threadIdx.x;   // grid 512
    float v = 0.f;
    #pragma unroll
    for (int z = 0; z < 8; ++z) v += Cp[(size_t)z*131072 + idx];
    Z[idx] = v;
}

// Cp[z](rows b*64..) = Q(:,b-block)^T * Z over K-chunk z*256
__global__ __launch_bounds__(256)
void lz_QTZ(const float* __restrict__ Qall, const float* __restrict__ Z, float* __restrict__ Cp)
{
    __shared__ float sA[2][16][68], sB[2][16][68];
    int z = blockIdx.x, b = blockIdx.y;
    float acc[4][4] = {};
    tile64d<true,false>(Qall, 2048, Z, 64, b*64, 0, z*256, z*256 + 256, acc, sA, sB);
    store_tile(Cp + (size_t)z*131072, 64, b*64, acc);
}

// Creo = sum_z Cp[z]; stash A-block rows [64s, 64s+64)
__global__ void lz_sumC(const float* __restrict__ Cp, float* __restrict__ Creo,
                        float* __restrict__ Ab, int s)
{
    int idx = blockIdx.x*256 + threadIdx.x;   // grid (s+1)*16
    float v = 0.f;
    #pragma unroll
    for (int z = 0; z < 8; ++z) v += Cp[(size_t)z*131072 + idx];
    Creo[idx] = v;
    if ((idx >> 6) >= 64*s) Ab[(size_t)s*4096 + (idx - s*4096)] = v;
}

// Cp[z] = Q(rows mt)(blocks j==z mod 8, j<=s) * Creo(blocks)
__global__ __launch_bounds__(256)
void lz_QC(const float* __restrict__ Qall, const float* __restrict__ Creo,
           float* __restrict__ Cp, int s)
{
    __shared__ float sA[2][16][68], sB[2][16][68];
    int z = blockIdx.x, mt = blockIdx.y;   // gridDim.x = nz <= 8
    float acc[4][4] = {};
    for (int j = z; j <= s; j += 8)
        tile64d<false,false>(Qall, 2048, Creo, 64, mt*64, 0, j*64, j*64 + 64, acc, sA, sB);
    store_tile(Cp + (size_t)z*131072, 64, mt*64, acc);
}

// Z'(rows w) = Z - sum_{z<nz} Cp[z]; Gp[w] = Z'_w^T Z'_w in f64
__global__ __launch_bounds__(256)
void lz_finZ(float* __restrict__ Z, const float* __restrict__ Cp, int nz,
             double* __restrict__ Gp)
{
    __shared__ float zb[64][65];
    int w = blockIdx.x, tid = threadIdx.x;
    for (int idx = tid; idx < 4096; idx += 256) {
        size_t o = (size_t)w*4096 + idx;
        float v = Z[o];
        for (int z = 0; z < nz; ++z) v -= Cp[(size_t)z*131072 + o];
        Z[o] = v;
        zb[idx >> 6][idx & 63] = v;
    }
    __syncthreads();
    int tx = tid & 15, ty = tid >> 4;
    double acc[4][4] = {};
    for (int r = 0; r < 64; ++r) {
        float av[4], bv[4];
        #pragma unroll
        for (int q = 0; q < 4; ++q) { av[q] = zb[r][ty*4 + q]; bv[q] = zb[r][tx*4 + q]; }
        #pragma unroll
        for (int i = 0; i < 4; ++i)
            #pragma unroll
            for (int j = 0; j < 4; ++j)
                acc[i][j] += (double)av[i] * (double)bv[j];
    }
    #pragma unroll
    for (int i = 0; i < 4; ++i)
        #pragma unroll
        for (int j = 0; j < 4; ++j)
            Gp[(size_t)w*4096 + (size_t)(ty*4 + i)*64 + tx*4 + j] = acc[i][j];
}

// f64 Cholesky of G = sum Gp (32 partials); Bb_s = R (f32); RinvF = R^{-1} (f32)
__global__ __launch_bounds__(256)
void lz_chol(const double* __restrict__ Gp, float* __restrict__ RinvF, float* __restrict__ BbS)
{
    __shared__ double G[64][65];
    __shared__ double Xs[64][65];
    __shared__ double lv[64];
    int tid = threadIdx.x;
    for (int idx = tid; idx < 4096; idx += 256) {
        double g = 0.0;
        for (int z = 0; z < 32; ++z) g += Gp[(size_t)z*4096 + idx];
        G[idx>>6][idx&63] = g;
    }
    __syncthreads();
    for (int k = 0; k < 64; ++k) {
        if (tid < 64) {
            double rkk = sqrt(fmax(G[k][k], 1e-40));
            lv[tid] = (tid == k) ? rkk : ((tid > k) ? G[k][tid]/rkk : 0.0);
        }
        __syncthreads();
        if (tid < 64 && tid >= k) G[k][tid] = lv[tid];
        for (int idx = tid; idx < 4096; idx += 256) {
            int i = idx>>6, j = idx&63;
            if (i > k && j >= i) G[i][j] -= lv[i]*lv[j];
        }
        __syncthreads();
    }
    for (int idx = tid; idx < 4096; idx += 256) {
        int i = idx>>6, j = idx&63;
        BbS[idx] = (j >= i) ? (float)G[i][j] : 0.f;
        Xs[i][j] = 0.0;
    }
    __syncthreads();
    if (tid < 64) {
        int j = tid;
        for (int i = j; i >= 0; --i) {
            double s2 = (i == j) ? 1.0 : 0.0;
            for (int k2 = i + 1; k2 <= j; ++k2) s2 -= G[i][k2]*Xs[k2][j];
            Xs[i][j] = s2 / G[i][i];
        }
    }
    __syncthreads();
    for (int idx = tid; idx < 4096; idx += 256)
        RinvF[idx] = (float)Xs[idx>>6][idx&63];
}

// Qnext(rows w) = Z'(rows w) * Rinv
__global__ __launch_bounds__(256)
void lz_apply(const float* __restrict__ Z, const float* __restrict__ Rinv, float* __restrict__ Qn)
{
    __shared__ float sA[2][16][68], sB[2][16][68];
    int w = blockIdx.x;
    float acc[4][4] = {};
    tile64d<false,false>(Z, 64, Rinv, 64, w*64, 0, 0, 64, acc, sA, sB);
    store_tile(Qn, 2048, w*64, acc);
}

// band[c*65+r] = T[c+r, c]
__global__ void assemble_band(const float* Ab, const float* Bb, float* band) {
    int idx = blockIdx.x*256 + threadIdx.x;
    if (idx >= 2048*65) return;
    int c = idx / 65, r = idx % 65;
    int row = c + r;
    float v = 0.f;
    if (row < 2048) {
        int j = c >> 6, q = c & 63, rr = q + r;
        if (rr <= 63) {
            const float* A = Ab + (size_t)j*4096;
            v = 0.5f*(A[rr*64 + q] + A[q*64 + rr]);
        } else if (j < 31) {
            int p = rr - 64;
            v = Bb[(size_t)j*4096 + p*64 + q];
        }
    }
    band[idx] = v;
}

// ---------------------------------------------------------------------------
// Pack helpers
// ---------------------------------------------------------------------------
__device__ __forceinline__
void pack_item(int idx, const float* __restrict__ src, const float* __restrict__ dv,
               ushort* __restrict__ Bh, ushort* __restrict__ Bl,
               ushort* __restrict__ Ch, ushort* __restrict__ Cl)
{
    int l = idx & 63, t = idx >> 6;
    int nb = t & 31, kc = t >> 5;
    int col = nb*16 + (l & 15);
    int k0 = kc*32 + ((l >> 4) << 3);
    ushort h8[8], l8[8], sh8[8], sl8[8];
    #pragma unroll
    for (int j = 0; j < 8; ++j) {
        int k = k0 + j;
        float v = src[(size_t)k*512 + col];
        ushort hb = bf16_rne(v);
        h8[j] = hb; l8[j] = bf16_rne(v - bf16_tof(hb));
        if (Ch) {
            float t2 = v * (1.0f / sqrtf(dv[k] + 1e-10f));
            ushort hb2 = bf16_rne(t2);
            sh8[j] = hb2; sl8[j] = bf16_rne(t2 - bf16_tof(hb2));
        }
    }
    uint4 hv, lv;
    hv.x = (unsigned)h8[0] | ((unsigned)h8[1] << 16);
    hv.y = (unsigned)h8[2] | ((unsigned)h8[3] << 16);
    hv.z = (unsigned)h8[4] | ((unsigned)h8[5] << 16);
    hv.w = (unsigned)h8[6] | ((unsigned)h8[7] << 16);
    lv.x = (unsigned)l8[0] | ((unsigned)l8[1] << 16);
    lv.y = (unsigned)l8[2] | ((unsigned)l8[3] << 16);
    lv.z = (unsigned)l8[4] | ((unsigned)l8[5] << 16);
    lv.w = (unsigned)l8[6] | ((unsigned)l8[7] << 16);
    *(uint4*)(Bh + (size_t)idx*8) = hv;
    *(uint4*)(Bl + (size_t)idx*8) = lv;
    if (Ch) {
        uint4 shv, slv;
        shv.x = (unsigned)sh8[0] | ((unsigned)sh8[1] << 16);
        shv.y = (unsigned)sh8[2] | ((unsigned)sh8[3] << 16);
        shv.z = (unsigned)sh8[4] | ((unsigned)sh8[5] << 16);
        shv.w = (unsigned)sh8[6] | ((unsigned)sh8[7] << 16);
        slv.x = (unsigned)sl8[0] | ((unsigned)sl8[1] << 16);
        slv.y = (unsigned)sl8[2] | ((unsigned)sl8[3] << 16);
        slv.z = (unsigned)sl8[4] | ((unsigned)sl8[5] << 16);
        slv.w = (unsigned)sl8[6] | ((unsigned)sl8[7] << 16);
        *(uint4*)(Ch + (size_t)idx*8) = shv;
        *(uint4*)(Cl + (size_t)idx*8) = slv;
    }
}

__global__ void pack_both(const float* __restrict__ src, const float* __restrict__ dv,
                          ushort* __restrict__ Bh, ushort* __restrict__ Bl,
                          ushort* __restrict__ Ch, ushort* __restrict__ Cl)
{
    int idx = blockIdx.x*256 + threadIdx.x;
    if (idx < 131072) pack_item(idx, src, dv, Bh, Bl, Ch, Cl);
}

__global__ void pack_A_L(const float* __restrict__ src, int Kld, int MB,
                         ushort* __restrict__ Ah, ushort* __restrict__ Al, int total)
{
    int idx = blockIdx.x*256 + threadIdx.x;
    if (idx >= total) return;
    int l = idx & 63, t = idx >> 6;
    int mb = t % MB, kc = t / MB;
    int m = mb*16 + (l & 15);
    int k0 = kc*32 + ((l >> 4) << 3);
    const float* p = src + (size_t)m*Kld + k0;
    float4 a = *(const float4*)p, b = *(const float4*)(p + 4);
    float vv[8] = {a.x,a.y,a.z,a.w,b.x,b.y,b.z,b.w};
    ushort h8[8], l8[8];
    #pragma unroll
    for (int j = 0; j < 8; ++j) {
        ushort hb = bf16_rne(vv[j]);
        h8[j] = hb; l8[j] = bf16_rne(vv[j] - bf16_tof(hb));
    }
    uint4 hv, lv;
    hv.x = (unsigned)h8[0] | ((unsigned)h8[1] << 16);
    hv.y = (unsigned)h8[2] | ((unsigned)h8[3] << 16);
    hv.z = (unsigned)h8[4] | ((unsigned)h8[5] << 16);
    hv.w = (unsigned)h8[6] | ((unsigned)h8[7] << 16);
    lv.x = (unsigned)l8[0] | ((unsigned)l8[1] << 16);
    lv.y = (unsigned)l8[2] | ((unsigned)l8[3] << 16);
    lv.z = (unsigned)l8[4] | ((unsigned)l8[5] << 16);
    lv.w = (unsigned)l8[6] | ((unsigned)l8[7] << 16);
    *(uint4*)(Ah + (size_t)idx*8) = hv;
    *(uint4*)(Al + (size_t)idx*8) = lv;
}

__global__ void pack_A_T(const float* __restrict__ src, int Mld, int MB,
                         ushort* __restrict__ Ah, int total)
{
    int idx = blockIdx.x*256 + threadIdx.x;
    if (idx >= total) return;
    int l = idx & 63, t = idx >> 6;
    int mb = t % MB, kc = t / MB;
    int m = mb*16 + (l & 15);
    int k0 = kc*32 + ((l >> 4) << 3);
    ushort h8[8];
    #pragma unroll
    for (int j = 0; j < 8; ++j)
        h8[j] = bf16_rne(src[(size_t)(k0 + j)*Mld + m]);
    uint4 hv;
    hv.x = (unsigned)h8[0] | ((unsigned)h8[1] << 16);
    hv.y = (unsigned)h8[2] | ((unsigned)h8[3] << 16);
    hv.z = (unsigned)h8[4] | ((unsigned)h8[5] << 16);
    hv.w = (unsigned)h8[6] | ((unsigned)h8[7] << 16);
    *(uint4*)(Ah + (size_t)idx*8) = hv;
}

// ---------------------------------------------------------------------------
// MFMA split-bf16 dual GEMM task
// ---------------------------------------------------------------------------
__device__ __forceinline__
void mfma_task(int t, const ushort* __restrict__ Lph, const ushort* __restrict__ Lpl,
               const ushort* __restrict__ Bh, const ushort* __restrict__ Bl,
               const ushort* __restrict__ Htp,
               const ushort* __restrict__ Bqh, const ushort* __restrict__ Bql,
               float* __restrict__ U, float* __restrict__ ME,
               ushort (*lA)[4096], ushort (*lB)[4096])
{
    const bool isU = (t < 64);
    const ushort* Ah = isU ? Lph : Htp;
    const ushort* Al = isU ? Lpl : nullptr;
    const ushort* Xh = isU ? Bh : Bqh;
    const ushort* Xl = isU ? Bl : Bql;
    float* C = isU ? U : ME;
    const int MB = isU ? 128 : 64;
    const int tmb = (isU ? (t >> 2) : ((t - 64) >> 2)) * 8;
    const int tnb = (t & 3) * 8;
    const int KC = 64;
    const int tid = threadIdx.x;
    const int lane = tid & 63, wave = tid >> 6;
    const int wr = wave >> 1, wc = wave & 1;

    f32x4 acc[4][4];
    #pragma unroll
    for (int i = 0; i < 4; ++i)
        #pragma unroll
        for (int j = 0; j < 4; ++j) acc[i][j] = (f32x4){0.f,0.f,0.f,0.f};

    uint4 rAh[2], rAl[2], rBh[2], rBl[2];
    auto loadregs = [&](int kc) {
        const uint4* pa = (const uint4*)(Ah + ((size_t)kc*MB + tmb)*512);
        rAh[0] = pa[tid]; rAh[1] = pa[tid + 256];
        if (Al) {
            const uint4* pl = (const uint4*)(Al + ((size_t)kc*MB + tmb)*512);
            rAl[0] = pl[tid]; rAl[1] = pl[tid + 256];
        }
        const uint4* pb = (const uint4*)(Xh + ((size_t)kc*32 + tnb)*512);
        rBh[0] = pb[tid]; rBh[1] = pb[tid + 256];
        const uint4* pc = (const uint4*)(Xl + ((size_t)kc*32 + tnb)*512);
        rBl[0] = pc[tid]; rBl[1] = pc[tid + 256];
    };

    loadregs(0);
    for (int kc = 0; kc < KC; ++kc) {
        __syncthreads();
        *(uint4*)&lA[0][tid*8]       = rAh[0];
        *(uint4*)&lA[0][(tid+256)*8] = rAh[1];
        if (Al) {
            *(uint4*)&lA[1][tid*8]       = rAl[0];
            *(uint4*)&lA[1][(tid+256)*8] = rAl[1];
        }
        *(uint4*)&lB[0][tid*8]       = rBh[0];
        *(uint4*)&lB[0][(tid+256)*8] = rBh[1];
        *(uint4*)&lB[1][tid*8]       = rBl[0];
        *(uint4*)&lB[1][(tid+256)*8] = rBl[1];
        if (kc + 1 < KC) loadregs(kc + 1);
        __syncthreads();

        short8 a_h[4], a_l[4], b_h[4], b_l[4];
        #pragma unroll
        for (int i = 0; i < 4; ++i) {
            a_h[i] = *(const short8*)&lA[0][(((wr*4 + i)*64) + lane)*8];
            if (Al) a_l[i] = *(const short8*)&lA[1][(((wr*4 + i)*64) + lane)*8];
        }
        #pragma unroll
        for (int j = 0; j < 4; ++j) {
            b_h[j] = *(const short8*)&lB[0][(((wc*4 + j)*64) + lane)*8];
            b_l[j] = *(const short8*)&lB[1][(((wc*4 + j)*64) + lane)*8];
        }
        #pragma unroll
        for (int i = 0; i < 4; ++i)
            #pragma unroll
            for (int j = 0; j < 4; ++j) {
                acc[i][j] = __builtin_amdgcn_mfma_f32_16x16x32_bf16(a_h[i], b_h[j], acc[i][j], 0, 0, 0);
                acc[i][j] = __builtin_amdgcn_mfma_f32_16x16x32_bf16(a_h[i], b_l[j], acc[i][j], 0, 0, 0);
                if (Al)
                    acc[i][j] = __builtin_amdgcn_mfma_f32_16x16x32_bf16(a_l[i], b_h[j], acc[i][j], 0, 0, 0);
            }
    }
    const int r0 = tmb*16 + wr*64, c0 = tnb*16 + wc*64;
    #pragma unroll
    for (int i = 0; i < 4; ++i)
        #pragma unroll
        for (int j = 0; j < 4; ++j) {
            int row = r0 + i*16 + ((lane >> 4) << 2);
            int col = c0 + j*16 + (lane & 15);
            #pragma unroll
            for (int r = 0; r < 4; ++r)
                C[(size_t)(row + r)*512 + col] = acc[i][j][r];
        }
}

__global__ __launch_bounds__(256, 2)
void mgemm_dual(const ushort* __restrict__ Lph, const ushort* __restrict__ Lpl,
                const ushort* __restrict__ Bh, const ushort* __restrict__ Bl,
                const ushort* __restrict__ Htp,
                const ushort* __restrict__ Bqh, const ushort* __restrict__ Bql,
                float* __restrict__ U, float* __restrict__ ME)
{
    __shared__ ushort lA[2][4096];
    __shared__ ushort lB[2][4096];
    int t = blockIdx.y * 4 + blockIdx.x;
    mfma_task(t, Lph, Lpl, Bh, Bl, Htp, Bqh, Bql, U, ME, lA, lB);
}

// ---------------------------------------------------------------------------
// Persistent MLP: layers 0..8, THREE barriers/layer.
// Phase A: finalize(k-1) + hgemm + tile-local pack + srow partials
// Phase C: mfma (u=L*h, mE=H^T*y) + coldot (qpart from srowp)
// Phase D: tail (edge energy + <h,u> dot)
// ---------------------------------------------------------------------------
__global__ __launch_bounds__(256, 1)
void mlp_persist(float* __restrict__ u, float* __restrict__ h,
                 const float* __restrict__ Wf, const float* __restrict__ Wm,
                 const ushort* __restrict__ Lph, const ushort* __restrict__ Lpl,
                 const ushort* __restrict__ Htp,
                 ushort* __restrict__ bpkh, ushort* __restrict__ bpkl,
                 ushort* __restrict__ bqh, ushort* __restrict__ bql,
                 const float* __restrict__ H, const float* __restrict__ dv,
                 const float* __restrict__ de,
                 float* __restrict__ mEb, float* __restrict__ srowp,
                 float* __restrict__ qpart,
                 float* __restrict__ parts512, float* __restrict__ parts16,
                 float* __restrict__ outp, int* __restrict__ bar)
{
    const int w = blockIdx.x, tid = threadIdx.x;
    __shared__ char smem[35072];
    __shared__ float red4[4];
    __shared__ float sRs[64];
    float (*sA)[68] = (float(*)[68])smem;
    float (*sB)[68] = (float(*)[68])(smem + 4352);
    float (*sT)[65] = (float(*)[65])smem;              // 16640 B (reuses sA/sB)
    ushort (*lA)[4096] = (ushort(*)[4096])smem;
    ushort (*lB)[4096] = (ushort(*)[4096])(smem + 16384);
    int ep = 0;
    const int mt = w >> 3, nt = w & 7;
    const int tx = tid & 15, ty = tid >> 4;

    for (int k = 0; k < 9; ++k) {
        const float* W = (k == 0) ? Wf : Wm + (size_t)(k-1)*262144;
        // ---- Phase A ----
        if (w == 0 && k > 0 && tid < 64) {
            float s = parts512[tid] + parts512[tid+64] + parts512[tid+128] + parts512[tid+192];
            for (int o = 32; o; o >>= 1) s += __shfl_down(s, o, 64);
            float x = (tid < 16) ? parts16[tid] : 0.f;
            for (int o = 32; o; o >>= 1) x += __shfl_down(x, o, 64);
            if (tid == 0) { outp[81920 + k - 1] = s; outp[81930 + k - 1] = x; }
        }
        {
            float acc[4][4] = {};
            tile64g<false,true>(u, 512, W, 512, mt*64, nt*64, 0, 512, acc, sA, sB);
            __syncthreads();   // sA/sB free; reuse as sT
            if (tid < 64) sRs[tid] = 1.0f / sqrtf(dv[mt*64 + tid] + 1e-10f);
            #pragma unroll
            for (int i = 0; i < 4; ++i)
                #pragma unroll
                for (int j = 0; j < 4; ++j) {
                    float v = fmaxf(acc[i][j], 0.f);
                    h[(size_t)(mt*64 + ty*4 + i)*512 + nt*64 + tx*4 + j] = v;
                    sT[ty*4 + i][tx*4 + j] = v;
                }
            __syncthreads();
            // pack this tile: 512 items (a in {0,1}, b in {0..3}, lane in {0..63})
            #pragma unroll
            for (int q = 0; q < 2; ++q) {
                int it = tid + q*256;
                int a = it >> 8, rem = it & 255;
                int b = rem >> 6, lane = rem & 63;
                int cl = b*16 + (lane & 15);
                int r0 = a*32 + ((lane >> 4) << 3);
                int idxg = (((2*mt + a)*32 + (4*nt + b))*64 + lane);
                ushort h8[8], l8[8], sh8[8], sl8[8];
                #pragma unroll
                for (int j = 0; j < 8; ++j) {
                    float v = sT[r0 + j][cl];
                    ushort hb = bf16_rne(v);
                    h8[j] = hb; l8[j] = bf16_rne(v - bf16_tof(hb));
                    float t2 = v * sRs[r0 + j];
                    ushort hb2 = bf16_rne(t2);
                    sh8[j] = hb2; sl8[j] = bf16_rne(t2 - bf16_tof(hb2));
                }
                uint4 hv, lv, shv, slv;
                hv.x = (unsigned)h8[0] | ((unsigned)h8[1] << 16);
                hv.y = (unsigned)h8[2] | ((unsigned)h8[3] << 16);
                hv.z = (unsigned)h8[4] | ((unsigned)h8[5] << 16);
                hv.w = (unsigned)h8[6] | ((unsigned)h8[7] << 16);
                lv.x = (unsigned)l8[0] | ((unsigned)l8[1] << 16);
                lv.y = (unsigned)l8[2] | ((unsigned)l8[3] << 16);
                lv.z = (unsigned)l8[4] | ((unsigned)l8[5] << 16);
                lv.w = (unsigned)l8[6] | ((unsigned)l8[7] << 16);
                shv.x = (unsigned)sh8[0] | ((unsigned)sh8[1] << 16);
                shv.y = (unsigned)sh8[2] | ((unsigned)sh8[3] << 16);
                shv.z = (unsigned)sh8[4] | ((unsigned)sh8[5] << 16);
                shv.w = (unsigned)sh8[6] | ((unsigned)sh8[7] << 16);
                slv.x = (unsigned)sl8[0] | ((unsigned)sl8[1] << 16);
                slv.y = (unsigned)sl8[2] | ((unsigned)sl8[3] << 16);
                slv.z = (unsigned)sl8[4] | ((unsigned)sl8[5] << 16);
                slv.w = (unsigned)sl8[6] | ((unsigned)sl8[7] << 16);
                *(uint4*)(bpkh + (size_t)idxg*8) = hv;
                *(uint4*)(bpkl + (size_t)idxg*8) = lv;
                *(uint4*)(bqh  + (size_t)idxg*8) = shv;
                *(uint4*)(bql  + (size_t)idxg*8) = slv;
            }
            // srow partials: thread tid<64 owns local row tid
            if (tid < 64) {
                float rs = sRs[tid];
                float ss = 0.f;
                for (int c = 0; c < 64; ++c) { float v = sT[tid][c]; ss += v*v; }
                srowp[(size_t)nt*2048 + mt*64 + tid] = ss * rs * rs;
            }
        }
        pbar(bar, ++ep, w, 256);
        // ---- Phase C ----
        if (w < 96) {
            mfma_task(w, Lph, Lpl, bpkh, bpkl, Htp, bqh, bql, u, mEb, lA, lB);
        } else if (w < 128) {
            int task = w - 96;
            int e = (task & 3)*256 + tid;
            int zc = task >> 2;
            float s = 0.f;
            for (int n = zc*256; n < zc*256 + 256; ++n) {
                float sr = 0.f;
                #pragma unroll
                for (int p2 = 0; p2 < 8; ++p2) sr += srowp[(size_t)p2*2048 + n];
                s += H[(size_t)n*1024 + e] * sr;
            }
            qpart[(size_t)zc*1024 + e] = s;
        }
        pbar(bar, ++ep, w, 256);
        // ---- Phase D ----
        if (w < 16) {
            int wave = tid >> 6, lane = tid & 63;
            float acc = 0.f;
            for (int t2 = 0; t2 < 16; ++t2) {
                int e = w*64 + wave*16 + t2;
                float me2 = 0.f;
                for (int f = lane; f < 512; f += 64) { float v = mEb[(size_t)e*512 + f]; me2 += v*v; }
                for (int o = 32; o; o >>= 1) me2 += __shfl_down(me2, o, 64);
                if (lane == 0) {
                    float q = 0.f;
                    for (int z = 0; z < 8; ++z) q += qpart[(size_t)z*1024 + e];
                    acc += (de[e]*q - me2) / (de[e] + 1e-10f);
                }
            }
            if (lane == 0) red4[wave] = acc;
            __syncthreads();
            if (tid == 0) parts16[w] = red4[0]+red4[1]+red4[2]+red4[3];
            __syncthreads();
        }
        {
            int lane = tid & 63;
            float dd = 0.f;
            #pragma unroll
            for (int g = 0; g < 2; ++g) {
                int row = w*8 + g*4 + (tid >> 6);
                for (int f = lane; f < 512; f += 64)
                    dd += h[(size_t)row*512 + f] * u[(size_t)row*512 + f];
            }
            for (int o = 32; o; o >>= 1) dd += __shfl_down(dd, o, 64);
            __syncthreads();
            if (lane == 0) red4[tid >> 6] = dd;
            __syncthreads();
            if (tid == 0) parts512[w] = red4[0]+red4[1]+red4[2]+red4[3];
        }
        pbar(bar, ++ep, w, 256);
    }
    if (w == 0 && tid < 64) {
        float s = parts512[tid] + parts512[tid+64] + parts512[tid+128] + parts512[tid+192];
        for (int o = 32; o; o >>= 1) s += __shfl_down(s, o, 64);
        float x = (tid < 16) ? parts16[tid] : 0.f;
        for (int o = 32; o; o >>= 1) x += __shfl_down(x, o, 64);
        if (tid == 0) { outp[81928] = s; outp[81938] = x; }
    }
}

// ---------------------------------------------------------------------------
// 64x64 f32 GEMM (layer 9 + small shapes), split-K
// ---------------------------------------------------------------------------
template<bool TA, bool TB>
__global__ __launch_bounds__(256)
void gemm_f32(const float* A, int lda, const float* B, int ldb,
              float* C, int ldc, float* Cpart,
              int M, int N, int K, float alpha, float beta, int relu)
{
    const int S = (int)gridDim.z, z = (int)blockIdx.z;
    const int kchunk = (K + S - 1) / S;
    const int k0 = z * kchunk;
    const int k1 = (K < k0 + kchunk) ? K : (k0 + kchunk);
    const int bm = blockIdx.y * 64, bn = blockIdx.x * 64;
    __shared__ float As[16][68];
    __shared__ float Bs[16][68];
    const int tid = threadIdx.x;
    const int tx = tid & 15, ty = tid >> 4;
    float acc[4][4] = {};
    for (int kk = k0; kk < k1; kk += 16) {
        for (int i = tid; i < 1024; i += 256) {
            int m, k;
            if (TA) { m = i & 63; k = i >> 6; } else { k = i & 15; m = i >> 4; }
            int gm = bm + m, gk = kk + k;
            float v = 0.f;
            if (gm < M && gk < k1) v = TA ? A[(size_t)gk*lda + gm] : A[(size_t)gm*lda + gk];
            As[k][m] = v;
        }
        for (int i = tid; i < 1024; i += 256) {
            int n, k;
            if (TB) { k = i & 15; n = i >> 4; } else { n = i & 63; k = i >> 6; }
            int gn = bn + n, gk = kk + k;
            float v = 0.f;
            if (gn < N && gk < k1) v = TB ? B[(size_t)gn*ldb + gk] : B[(size_t)gk*ldb + gn];
            Bs[k][n] = v;
        }
        __syncthreads();
        #pragma unroll
        for (int k = 0; k < 16; ++k) {
            float4 ra4 = *reinterpret_cast<const float4*>(&As[k][ty*4]);
            float4 rb4 = *reinterpret_cast<const float4*>(&Bs[k][tx*4]);
            float ra[4] = {ra4.x, ra4.y, ra4.z, ra4.w};
            float rb[4] = {rb4.x, rb4.y, rb4.z, rb4.w};
            #pragma unroll
            for (int i = 0; i < 4; ++i)
                #pragma unroll
                for (int j = 0; j < 4; ++j)
                    acc[i][j] += ra[i] * rb[j];
        }
        __syncthreads();
    }
    if (S == 1) {
        #pragma unroll
        for (int i = 0; i < 4; ++i) {
            int gm = bm + ty*4 + i;
            if (gm >= M) continue;
            #pragma unroll
            for (int j = 0; j < 4; ++j) {
                int gn = bn + tx*4 + j;
                if (gn >= N) continue;
                float v = alpha * acc[i][j];
                if (beta != 0.f) v += beta * C[(size_t)gm*ldc + gn];
                if (relu) v = fmaxf(v, 0.f);
                C[(size_t)gm*ldc + gn] = v;
            }
        }
    } else {
        float* P = Cpart + (size_t)z * M * N;
        #pragma unroll
        for (int i = 0; i < 4; ++i) {
            int gm = bm + ty*4 + i;
            if (gm >= M) continue;
            #pragma unroll
            for (int j = 0; j < 4; ++j) {
                int gn = bn + tx*4 + j;
                if (gn >= N) continue;
                P[(size_t)gm*N + gn] = alpha * acc[i][j];
            }
        }
    }
}

__global__ void reduce_parts(const float* Cpart, float* C, int M, int N, int ldc,
                             int S, float beta, int relu)
{
    int total = M * N;
    for (int idx = blockIdx.x*256 + threadIdx.x; idx < total; idx += gridDim.x*256) {
        float s = 0.f;
        for (int z = 0; z < S; ++z) s += Cpart[(size_t)z*total + idx];
        int mm = idx / N, nn = idx % N;
        float v = s;
        if (beta != 0.f) v += beta * C[(size_t)mm*ldc + nn];
        if (relu) v = fmaxf(v, 0.f);
        C[(size_t)mm*ldc + nn] = v;
    }
}

// ---------------------------------------------------------------------------
// Setup / layer-9 utility kernels
// ---------------------------------------------------------------------------
__global__ void row_deg(const float* H, float* dv) {
    int row = blockIdx.x*4 + (threadIdx.x >> 6);
    int lane = threadIdx.x & 63;
    if (row >= 2048) return;
    float s = 0.f;
    for (int e = lane; e < 1024; e += 64) s += H[(size_t)row*1024 + e];
    for (int o = 32; o; o >>= 1) s += __shfl_down(s, o, 64);
    if (lane == 0) dv[row] = s;
}

__global__ void coldot_part(const float* H, const float* w, float* part) {
    int e = blockIdx.x*256 + threadIdx.x;
    int zc = blockIdx.y;
    float s = 0.f;
    if (w) {
        for (int n = zc*256; n < zc*256 + 256; ++n) s += H[(size_t)n*1024 + e] * w[n];
    } else {
        for (int n = zc*256; n < zc*256 + 256; ++n) s += H[(size_t)n*1024 + e];
    }
    part[(size_t)zc*1024 + e] = s;
}
__global__ void coldot_fin(const float* part, float* outp) {
    int e = blockIdx.x*256 + threadIdx.x;
    float s = 0.f;
    for (int z = 0; z < 8; ++z) s += part[(size_t)z*1024 + e];
    outp[e] = s;
}

__global__ void dotsrow(const float* h, const float* u, int F, const float* dv,
                        float* srow, float* yout, float* parts)
{
    int row = blockIdx.x*4 + (threadIdx.x >> 6);
    int lane = threadIdx.x & 63;
    __shared__ float a4[4];
    float rs = 1.0f / sqrtf(dv[row] + 1e-10f);
    float ss = 0.f, dd = 0.f;
    for (int f = lane; f < F; f += 64) {
        float hv = h[(size_t)row*F + f];
        float t = hv * rs;
        if (yout) yout[(size_t)row*F + f] = t;
        ss += t*t;
        dd += hv * u[(size_t)row*F + f];
    }
    for (int o = 32; o; o >>= 1) { ss += __shfl_down(ss, o, 64); dd += __shfl_down(dd, o, 64); }
    if (lane == 0) { srow[row] = ss; a4[threadIdx.x >> 6] = dd; }
    __syncthreads();
    if (threadIdx.x == 0) parts[blockIdx.x] = a4[0]+a4[1]+a4[2]+a4[3];
}

__global__ void edge_energy(const float* m, int F, const float* de, const float* qpart,
                            float* partials) {
    int wave = threadIdx.x >> 6, lane = threadIdx.x & 63;
    __shared__ float acc4[4];
    float acc = 0.f;
    for (int t = 0; t < 16; ++t) {
        int e = blockIdx.x*64 + wave*16 + t;
        float me2 = 0.f;
        for (int f = lane; f < F; f += 64) { float v = m[(size_t)e*F + f]; me2 += v*v; }
        for (int o = 32; o; o >>= 1) me2 += __shfl_down(me2, o, 64);
        if (lane == 0) {
            float q = 0.f;
            for (int z = 0; z < 8; ++z) q += qpart[(size_t)z*1024 + e];
            acc += (de[e]*q - me2) / (de[e] + 1e-10f);
        }
    }
    if (lane == 0) acc4[wave] = acc;
    __syncthreads();
    if (threadIdx.x == 0) partials[blockIdx.x] = acc4[0]+acc4[1]+acc4[2]+acc4[3];
}

__global__ void finalize2(const float* p512, const float* p16, float* oe, float* ox) {
    __shared__ float red[256];
    int tid = threadIdx.x;
    red[tid] = p512[tid] + p512[tid + 256];
    __syncthreads();
    for (int st = 128; st; st >>= 1) { if (tid < st) red[tid] += red[tid+st]; __syncthreads(); }
    if (tid == 0) *oe = red[0];
    __syncthreads();
    red[tid] = (tid < 16) ? p16[tid] : 0.f;
    __syncthreads();
    for (int st = 128; st; st >>= 1) { if (tid < st) red[tid] += red[tid+st]; __syncthreads(); }
    if (tid == 0) *ox = red[0];
}

__global__ void logsoftmax(const float* xf, float* outp) {
    __shared__ float red[256];
    int c = blockIdx.x, tid = threadIdx.x;
    float mx = -3.0e38f;
    for (int n = tid; n < 2048; n += 256) mx = fmaxf(mx, xf[(size_t)n*40 + c]);
    red[tid] = mx; __syncthreads();
    for (int st = 128; st; st >>= 1) { if (tid < st) red[tid] = fmaxf(red[tid], red[tid+st]); __syncthreads(); }
    mx = red[0]; __syncthreads();
    float s = 0.f;
    for (int n = tid; n < 2048; n += 256) s += expf(xf[(size_t)n*40 + c] - mx);
    red[tid] = s; __syncthreads();
    for (int st = 128; st; st >>= 1) { if (tid < st) red[tid] += red[tid+st]; __syncthreads(); }
    float lse = mx + logf(red[0]);
    for (int n = tid; n < 2048; n += 256) outp[(size_t)n*40 + c] = xf[(size_t)n*40 + c] - lse;
}

// ---------------------------------------------------------------------------
// Sturm count via band LDL^T — ONE barrier per column (round-11 version).
// ---------------------------------------------------------------------------
__global__ __launch_bounds__(256)
void band_count(const float* __restrict__ band, const double* __restrict__ shifts,
                int* __restrict__ counts)
{
    __shared__ double win[66][66];
    const int tid = threadIdx.x;
    const double sigma = shifts[blockIdx.x];
    int ei[9], ej[9];
    {
        int i = 1, S = 0;
        #pragma unroll
        for (int k = 0; k < 9; ++k) {
            int T = tid + k*256;
            if (T < 2080) {
                while (S + (65 - i) <= T) { S += 65 - i; ++i; }
                ei[k] = i; ej[k] = i + (T - S);
            } else { ei[k] = 0; ej[k] = 0; }
        }
    }
    for (int idx = tid; idx < 65*65; idx += 256) {
        int c0 = idx / 65, r = idx % 65;
        win[c0][r] = (double)band[c0*65 + r] - (r == 0 ? sigma : 0.0);
    }
    __syncthreads();
    int cnt = 0;
    for (int c = 0; c < 2048; ++c) {
        const int p = c % 66;
        double d = win[p][0];
        if (fabs(d) < 1e-100) d = (d < 0 ? -1e-100 : 1e-100);
        if (d < 0) cnt++;
        double inv = 1.0 / d;
        #pragma unroll
        for (int k = 0; k < 9; ++k) {
            int i = ei[k];
            if (i) {
                int j = ej[k];
                int r2 = p + i; if (r2 >= 66) r2 -= 66;
                win[r2][j - i] -= win[p][i] * inv * win[p][j];
            }
        }
        int cn = c + 65;
        int slot = p + 65; if (slot >= 66) slot -= 66;
        if (tid < 65)
            win[slot][tid] = (cn < 2048)
                ? ((double)band[(size_t)cn*65 + tid] - (tid == 0 ? sigma : 0.0)) : 0.0;
        __syncthreads();
    }
    if (tid == 0) counts[blockIdx.x] = cnt;
}

__global__ void bisect(double* shifts, const int* counts, double* st, float* gap_out, int mode) {
    if (threadIdx.x != 0) return;
    if (mode == 0) {
        shifts[0] = 1e-10;
        double l0 = log(1e-6), l1 = log(0.5);
        for (int i = 1; i < NSHIFT; ++i) shifts[i] = exp(l0 + (l1 - l0)*(i - 1)/(double)(NSHIFT - 2));
        return;
    }
    if (mode == 1) {
        int n0 = counts[0];
        double lo = shifts[NSHIFT-1], hi = 1.5;
        for (int i = 1; i < NSHIFT; ++i) if (counts[i] > n0) { lo = shifts[i-1]; hi = shifts[i]; break; }
        st[0] = lo; st[1] = hi; st[2] = (double)n0;
        for (int i = 0; i < NSHIFT; ++i) shifts[i] = lo + (hi - lo)*(i + 1)/(double)(NSHIFT + 1);
        return;
    }
    int n0 = (int)st[2];
    double lo = st[0], hi = st[1];
    double nlo = shifts[NSHIFT-1], nhi = hi;
    for (int i = 0; i < NSHIFT; ++i) if (counts[i] > n0) { nhi = shifts[i]; nlo = (i == 0) ? lo : shifts[i-1]; break; }
    *gap_out = (float)(0.5*(nlo + nhi));
}

// ---------------------------------------------------------------------------
// Spectral norms
// ---------------------------------------------------------------------------
__global__ __launch_bounds__(256)
void gram9(const float* __restrict__ Wf, const float* __restrict__ Wm, float* __restrict__ sG)
{
    int mi = blockIdx.z;
    const float* W = (mi == 0) ? Wf : Wm + (size_t)(mi-1)*262144;
    __shared__ float sA[16][68], sB[16][68];
    int tid = threadIdx.x, tx = tid & 15, ty = tid >> 4;
    int bm = blockIdx.y*64, bn = blockIdx.x*64;
    float acc[4][4] = {};
    for (int kk = 0; kk < 512; kk += 16) {
        __syncthreads();
        for (int i = tid; i < 1024; i += 256) { int m = i&63, k = i>>6; sA[k][m] = W[(size_t)(kk+k)*512 + bm+m]; }
        for (int i = tid; i < 1024; i += 256) { int n = i&63, k = i>>6; sB[k][n] = W[(size_t)(kk+k)*512 + bn+n]; }
        __syncthreads();
        #pragma unroll
        for (int k = 0; k < 16; ++k) {
            float4 a4 = *(const float4*)&sA[k][ty*4];
            float4 b4 = *(const float4*)&sB[k][tx*4];
            float av[4]={a4.x,a4.y,a4.z,a4.w}, bv[4]={b4.x,b4.y,b4.z,b4.w};
            #pragma unroll
            for (int i = 0; i < 4; ++i)
                #pragma unroll
                for (int j = 0; j < 4; ++j) acc[i][j] += av[i]*bv[j];
        }
    }
    float* C = sG + (size_t)mi*262144;
    #pragma unroll
    for (int i = 0; i < 4; ++i)
        #pragma unroll
        for (int j = 0; j < 4; ++j)
            C[(size_t)(bm + ty*4 + i)*512 + bn + tx*4 + j] = acc[i][j];
}

__global__ __launch_bounds__(256)
void snorm_lanczos(const float* Gall, const float* Wl, float* outp) {
    int w = blockIdx.x, tid = threadIdx.x;
    int n = (w < 9) ? 512 : 40;
    const float* G = Gall + (size_t)w*262144;
    __shared__ float g40[1600];
    __shared__ float v[512], vp[512], wv[512], red[256];
    __shared__ float al[32], be[32];
    if (w == 9) {
        for (int p = tid; p < 1600; p += 256) {
            int i = p / 40, j = p % 40;
            float s = 0.f;
            for (int k2 = 0; k2 < 512; ++k2) s += Wl[(size_t)i*512 + k2]*Wl[(size_t)j*512 + k2];
            g40[p] = s;
        }
        __syncthreads();
    }
    float inv0 = 1.f / sqrtf((float)n);
    for (int i = tid; i < n; i += 256) { v[i] = inv0; vp[i] = 0.f; }
    __syncthreads();
    float beta_prev = 0.f;
    for (int s = 0; s < 32; ++s) {
        for (int r = tid; r < n; r += 256) {
            float sum = 0.f;
            if (w < 9) { const float* row = G + (size_t)r*512; for (int k2 = 0; k2 < 512; ++k2) sum += row[k2]*v[k2]; }
            else       { const float* row = &g40[r*40];        for (int k2 = 0; k2 < 40;  ++k2) sum += row[k2]*v[k2]; }
            wv[r] = sum;
        }
        __syncthreads();
        float p = 0.f;
        for (int i = tid; i < n; i += 256) p += v[i]*wv[i];
        red[tid] = p; __syncthreads();
        for (int st = 128; st; st >>= 1) { if (tid < st) red[tid] += red[tid+st]; __syncthreads(); }
        float alpha = red[0]; __syncthreads();
        for (int i = tid; i < n; i += 256) wv[i] -= alpha*v[i] + beta_prev*vp[i];
        __syncthreads();
        p = 0.f;
        for (int i = tid; i < n; i += 256) p += wv[i]*wv[i];
        red[tid] = p; __syncthreads();
        for (int st = 128; st; st >>= 1) { if (tid < st) red[tid] += red[tid+st]; __syncthreads(); }
        float beta = sqrtf(fmaxf(red[0], 0.f)); __syncthreads();
        if (tid == 0) { al[s] = alpha; be[s] = beta; }
        float ib = 1.f / fmaxf(beta, 1e-20f);
        for (int i = tid; i < n; i += 256) { float t = v[i]; vp[i] = t; v[i] = wv[i]*ib; }
        beta_prev = beta;
        __syncthreads();
    }
    if (tid == 0) {
        float hi = 0.f;
        for (int s = 0; s < 32; ++s) {
            float g2 = al[s] + be[s] + (s ? be[s-1] : 0.f);
            hi = fmaxf(hi, g2);
        }
        float lo = 0.f;
        for (int it = 0; it < 48; ++it) {
            float mid = 0.5f*(lo + hi);
            float d = al[0] - mid; int c2 = (d < 0.f);
            for (int s = 1; s < 32; ++s) {
                float dp = d;
                if (fabsf(dp) < 1e-25f) dp = (dp < 0.f) ? -1e-25f : 1e-25f;
                d = (al[s] - mid) - be[s-1]*be[s-1]/dp;
                c2 += (d < 0.f);
            }
            if (c2 == 32) hi = mid; else lo = mid;
        }
        outp[w] = sqrtf(fmaxf(0.5f*(lo + hi), 0.f));
    }
}

// ---------------------------------------------------------------------------
// Host driver
// ---------------------------------------------------------------------------
static void gemm64(hipStream_t st, int ta, int tb, int M, int N, int K,
                   const float* A, int lda, const float* B, int ldb,
                   float* C, int ldc, float alpha, float beta, int relu,
                   float* Cpart, int S)
{
    dim3 grid((unsigned)((N + 63)/64), (unsigned)((M + 63)/64), (unsigned)S);
    if (!ta && !tb)      gemm_f32<false,false><<<grid,256,0,st>>>(A,lda,B,ldb,C,ldc,Cpart,M,N,K,alpha,beta,relu);
    else if (!ta && tb)  gemm_f32<false,true ><<<grid,256,0,st>>>(A,lda,B,ldb,C,ldc,Cpart,M,N,K,alpha,beta,relu);
    else if (ta && !tb)  gemm_f32<true ,false><<<grid,256,0,st>>>(A,lda,B,ldb,C,ldc,Cpart,M,N,K,alpha,beta,relu);
    else                 gemm_f32<true ,true ><<<grid,256,0,st>>>(A,lda,B,ldb,C,ldc,Cpart,M,N,K,alpha,beta,relu);
    if (S > 1) {
        int total = M * N;
        int g = (total + 255)/256; if (g > 2048) g = 2048;
        reduce_parts<<<g,256,0,st>>>(Cpart, C, M, N, ldc, S, beta, relu);
    }
}

extern "C" void kernel_launch(void* const* d_in, const int* in_sizes, int n_in,
                              void* d_out, int out_size, void* d_ws, size_t ws_size,
                              hipStream_t stream)
{
    (void)in_sizes; (void)n_in; (void)out_size; (void)ws_size;
    const float* X  = (const float*)d_in[0];
    const float* Lm = (const float*)d_in[1];
    const float* H  = (const float*)d_in[2];
    const float* Wf = (const float*)d_in[3];
    const float* Wm = (const float*)d_in[4];
    const float* Wl = (const float*)d_in[5];
    float* out = (float*)d_out;

    float* ws = (float*)d_ws;
    size_t off = 0;
    auto alloc = [&](size_t n) { float* p = ws + off; off += (n + 255) & ~(size_t)255; return p; };
    float* Lph_f  = alloc((size_t)2097152);   // L hi pack (ushort) | lancz Qall lo-half
    float* Lpl_f  = alloc((size_t)2097152);   // L lo pack          | Qall hi-half
    float* Htp_f  = alloc((size_t)1048576);   // H^T pack           | Z/Creo/Ab/Bb/band/Rinv
    float* bpkh_f = alloc((size_t)524288);    // B pack hi          | lancz Gp (f64)
    float* bpkl_f = alloc((size_t)524288);    // B pack lo
    float* h      = alloc((size_t)2048*512);
    float* u      = alloc((size_t)2048*512);
    float* mEb    = alloc((size_t)1024*512);  // mE | layer9: h9/y9/mE9
    float* Cpart  = alloc((size_t)1024*1024); // bq packs | split-K partials | lancz Cp
    float* srowp  = alloc((size_t)8*2048);    // per-column-block srow partials
    float* dv     = alloc(2048);
    float* de     = alloc(1024);
    float* srow   = alloc(2048);
    float* qpart  = alloc(8*1024);
    float* parts512 = alloc(512);
    float* parts16  = alloc(256);
    double* shifts  = (double*)alloc(2*NSHIFT);
    double* bstate  = (double*)alloc(8);
    int* counts     = (int*)alloc(NSHIFT);
    int* barbase    = (int*)alloc(16384);

    ushort* Lph  = (ushort*)Lph_f;
    ushort* Lpl  = (ushort*)Lpl_f;
    ushort* Htp  = (ushort*)Htp_f;
    ushort* bpkh = (ushort*)bpkh_f;
    ushort* bpkl = (ushort*)bpkl_f;
    ushort* bqh  = (ushort*)Cpart;
    ushort* bql  = (ushort*)(Cpart + 524288);
    int* barM = barbase;
    // lancz-phase aliases (MLP packs dead by then)
    float* Qall  = Lph_f;                // 2048*2048
    float* Z     = Htp_f;                // 2048*64
    float* Creo  = Htp_f + 131072;       // 2048*64
    float* Ab    = Htp_f + 262144;       // 32*64*64
    float* Bb    = Htp_f + 393216;       // 32*64*64
    float* band  = Htp_f + 524288;       // 2048*65
    float* Rinv  = Htp_f + 658432;       // 64*64
    double* GpD  = (double*)bpkh_f;      // 32*4096 f64 Gram partials
    float* sG    = Qall;                 // snorm Grams
    float* h9  = mEb;                    // 2048*40
    float* y9  = mEb + 131072;           // 2048*40
    float* mE9 = mEb + 262144;           // 1024*40

    // ---- setup ----
    init_misc<<<16,256,0,stream>>>(barbase);
    pack_A_L<<<2048,256,0,stream>>>(Lm, 2048, 128, Lph, Lpl, 524288);
    pack_A_T<<<1024,256,0,stream>>>(H, 1024, 64, Htp, 262144);
    row_deg<<<512,256,0,stream>>>(H, dv);
    coldot_part<<<dim3(4,8),256,0,stream>>>(H, nullptr, qpart);
    coldot_fin<<<4,256,0,stream>>>(qpart, de);

    // ---- u0 = L x ----
    pack_both<<<512,256,0,stream>>>(X, dv, bpkh, bpkl, nullptr, nullptr);
    mgemm_dual<<<dim3(4,16),256,0,stream>>>(Lph, Lpl, bpkh, bpkl, Htp, bqh, bql, u, mEb);

    // ---- layers 0..8: persistent kernel (3 barriers/layer, tile-local pack) ----
    mlp_persist<<<256,256,0,stream>>>(u, h, Wf, Wm, Lph, Lpl, Htp,
                                      bpkh, bpkl, bqh, bql, H, dv, de,
                                      mEb, srowp, qpart, parts512, parts16, out, barM);

    // ---- layer 9 (Fo=40, f32 vector path) ----
    gemm64(stream, 0,1, 2048,40,512, u,512, Wl,512, h9,40, 1.f,0.f,1, Cpart,8);
    gemm64(stream, 0,0, 2048,40,2048, Lm,2048, h9,40, u,40, 1.f,0.f,0, Cpart,8);
    dotsrow<<<512,256,0,stream>>>(h9, u, 40, dv, srow, y9, parts512);
    coldot_part<<<dim3(4,8),256,0,stream>>>(H, srow, qpart);
    gemm64(stream, 1,0, 1024,40,2048, H,1024, y9,40, mE9,40, 1.f,0.f,0, Cpart,8);
    edge_energy<<<16,256,0,stream>>>(mE9, 40, de, qpart, parts16);
    finalize2<<<1,256,0,stream>>>(parts512, parts16, out + 81929, out + 81939);
    logsoftmax<<<40,256,0,stream>>>(h9, out);

    // ---- block Lanczos: round-11 8-kernel structure ----
    init_q0<<<512,256,0,stream>>>(Qall);
    for (int s = 0; s < 32; ++s) {
        lz_LQ<<<dim3(8,32),256,0,stream>>>(Lm, Qall + 64*s, Cpart);
        lz_sumZ<<<512,256,0,stream>>>(Cpart, Z);
        lz_QTZ<<<dim3(8,(unsigned)(s+1)),256,0,stream>>>(Qall, Z, Cpart);
        lz_sumC<<<(s+1)*16,256,0,stream>>>(Cpart, Creo, Ab, s);
        if (s == 31) break;
        int nz = (s + 1 < 8) ? s + 1 : 8;
        lz_QC<<<dim3((unsigned)nz,32),256,0,stream>>>(Qall, Creo, Cpart, s);
        lz_finZ<<<32,256,0,stream>>>(Z, Cpart, nz, GpD);
        lz_chol<<<1,256,0,stream>>>(GpD, Rinv, Bb + (size_t)s*4096);
        lz_apply<<<32,256,0,stream>>>(Z, Rinv, Qall + (size_t)64*(s+1));
    }
    assemble_band<<<520,256,0,stream>>>(Ab, Bb, band);

    // ---- Sturm bisection (2 rounds, single-barrier band_count) ----
    bisect<<<1,64,0,stream>>>(shifts, counts, bstate, out + 81950, 0);
    band_count<<<NSHIFT,256,0,stream>>>(band, shifts, counts);
    bisect<<<1,64,0,stream>>>(shifts, counts, bstate, out + 81950, 1);
    band_count<<<NSHIFT,256,0,stream>>>(band, shifts, counts);
    bisect<<<1,64,0,stream>>>(shifts, counts, bstate, out + 81950, 3);

    // ---- spectral norms ----
    gram9<<<dim3(8,8,9),256,0,stream>>>(Wf, Wm, sG);
    snorm_lanczos<<<10,256,0,stream>>>(sG, Wl, out + 81940);
}